// Round 8
// baseline (203.250 us; speedup 1.0000x reference)
//
#include <hip/hip_runtime.h>
#include <math.h>

#define NGRAPH 256
#define NPG 64
#define NFEAT 64
#define HC 504
#define NLAY 4
#define EPER 1024
#define NTRIU 2016
#define DCAT 4032
#define HID1 1024
#define HID2 512

#define GCN_LDS (65536 + 73728 + 16384)   // cur + xwt + ahl = 155648 B

typedef __attribute__((ext_vector_type(8))) short bfrag8;   // 8 bf16 in 4 VGPRs
typedef __attribute__((ext_vector_type(4))) float f32x4;

struct __align__(8) us4 { unsigned short a, b, c, d; };

__device__ __forceinline__ unsigned short f2b(float f) {
    union { float f; unsigned u; } v; v.f = f;
    unsigned r = (v.u + 0x7fffu + ((v.u >> 16) & 1u)) >> 16;   // RNE
    return (unsigned short)r;
}
__device__ __forceinline__ float b2f(unsigned short h) {
    union { unsigned u; float f; } v; v.u = ((unsigned)h) << 16;
    return v.f;
}

// ---------------------------------------------------------------------------
// Weight transpose+convert (row layout): Wt[n][k] = bf16(W[k][n])
// ---------------------------------------------------------------------------
__global__ void convWt(const float* __restrict__ W, unsigned short* __restrict__ Wt,
                       int K, int N, int KP, long long sStride, long long dStride)
{
    W  += (size_t)blockIdx.z * sStride;
    Wt += (size_t)blockIdx.z * dStride;
    __shared__ float T[32][33];
    int k0 = blockIdx.y * 32, n0 = blockIdx.x * 32;
    int tx = threadIdx.x, ty = threadIdx.y;
#pragma unroll
    for (int j = 0; j < 32; j += 8) {
        int k = k0 + ty + j, n = n0 + tx;
        T[ty + j][tx] = (k < K && n < N) ? W[(size_t)k * N + n] : 0.f;
    }
    __syncthreads();
#pragma unroll
    for (int j = 0; j < 32; j += 8) {
        int n = n0 + ty + j, k = k0 + tx;
        Wt[(size_t)n * KP + k] = f2b(T[tx][ty + j]);
    }
}

// ---------------------------------------------------------------------------
// Weight convert to MFMA-fragment-major layout (for gcn_all):
// elem (n,k) -> ((n>>4)*(KL/32) + (k>>5))*512 + ((k>>3)&3)*128 + (n&15)*8 + (k&7)
// ---------------------------------------------------------------------------
__global__ void convW4(const float* __restrict__ W, unsigned short* __restrict__ W4,
                       int K, int N, int KL, long long sStride, long long dStride)
{
    W  += (size_t)blockIdx.z * sStride;
    W4 += (size_t)blockIdx.z * dStride;
    __shared__ float T[32][33];
    int k0 = blockIdx.y * 32, n0 = blockIdx.x * 32;
    int tx = threadIdx.x, ty = threadIdx.y;
#pragma unroll
    for (int j = 0; j < 32; j += 8) {
        int k = k0 + ty + j, n = n0 + tx;
        T[ty + j][tx] = (k < K && n < N) ? W[(size_t)k * N + n] : 0.f;
    }
    __syncthreads();
#pragma unroll
    for (int j = 0; j < 32; j += 8) {
        int n = n0 + ty + j, k = k0 + tx;
        int idx = ((n >> 4) * (KL >> 5) + (k >> 5)) * 512
                + (((k >> 3) & 3) << 7) + ((n & 15) << 3) + (k & 7);
        W4[idx] = f2b(T[tx][ty + j]);
    }
}

// ---------------------------------------------------------------------------
// One GCN layer, one graph, 16 waves: wave wv owns 32 cols [wv*32, wv*32+32).
// Phase 1: XW = cur @ W^T (W fragment-major from L2, depth-2 prefetch),
//          write XW^T to wave-private xwt cols (us4).
// Phase 2 (SWAPPED): Y^T-tile = mfma(A=XW^T frag, B=Adj^T frag) so each lane
//          holds 4 consecutive feature-cols of ONE node -> us4 writeback to
//          row-major cur (2-way banks, no scalar stores) + shfl pool.
// ---------------------------------------------------------------------------
template<int KL>
__device__ __forceinline__ void gcn_layer(const unsigned short* __restrict__ W4,
                                          const float* __restrict__ bias,
                                          unsigned short* cur, unsigned short* xwt,
                                          const unsigned short* ahl,
                                          float* __restrict__ hsg,
                                          int wv, int lm, int lh)
{
    constexpr int KTS = KL >> 5;
    const int colw = wv << 5;             // 32 cols per wave
    const int kswz = (lm & 7) << 3;
    const int lane8 = ((lh << 4) + lm) << 3;   // lane * 8

    f32x4 acc[4][2];
#pragma unroll
    for (int m0 = 0; m0 < 4; ++m0)
#pragma unroll
        for (int cc = 0; cc < 2; ++cc) acc[m0][cc] = (f32x4){0.f, 0.f, 0.f, 0.f};

    // ---- phase 1: feature GEMM with depth-2 weight prefetch ----
    bfrag8 bq[2][2];
#pragma unroll
    for (int cc = 0; cc < 2; ++cc)
        bq[0][cc] = *(const bfrag8*)(const void*)&W4[(size_t)((wv * 2 + cc) * KTS + 0) * 512 + lane8];
    if (KTS > 1) {
#pragma unroll
        for (int cc = 0; cc < 2; ++cc)
            bq[1][cc] = *(const bfrag8*)(const void*)&W4[(size_t)((wv * 2 + cc) * KTS + 1) * 512 + lane8];
    }
#pragma unroll
    for (int kt = 0; kt < KTS; ++kt) {
        bfrag8 a[4];
#pragma unroll
        for (int m0 = 0; m0 < 4; ++m0)
            a[m0] = *(const bfrag8*)(const void*)&cur[(m0 * 16 + lm) * 512 + ((kt * 32 + (lh << 3)) ^ kswz)];
        bfrag8 bc[2];
        bc[0] = bq[kt & 1][0]; bc[1] = bq[kt & 1][1];
        if (kt + 2 < KTS) {
#pragma unroll
            for (int cc = 0; cc < 2; ++cc)
                bq[kt & 1][cc] = *(const bfrag8*)(const void*)&W4[(size_t)((wv * 2 + cc) * KTS + kt + 2) * 512 + lane8];
        }
#pragma unroll
        for (int cc = 0; cc < 2; ++cc)
#pragma unroll
            for (int m0 = 0; m0 < 4; ++m0)
                acc[m0][cc] = __builtin_amdgcn_mfma_f32_16x16x32_bf16(a[m0], bc[cc], acc[m0][cc], 0, 0, 0);
    }
    __syncthreads();   // all waves' cur reads complete before epilogue rewrites cur

    // ---- write XW^T to wave-private xwt cols (us4; no barrier needed) ----
#pragma unroll
    for (int cc = 0; cc < 2; ++cc) {
        const int c = colw + cc * 16 + lm;
#pragma unroll
        for (int m0 = 0; m0 < 4; ++m0) {
            us4 p;
            p.a = f2b(acc[m0][cc][0]); p.b = f2b(acc[m0][cc][1]);
            p.c = f2b(acc[m0][cc][2]); p.d = f2b(acc[m0][cc][3]);
            *(us4*)(void*)&xwt[c * 72 + m0 * 16 + (lh << 2)] = p;
        }
    }

    // ---- phase 2 (swapped): acc2[cc][n0] = Y^T tile ----
    f32x4 acc2[2][4];
#pragma unroll
    for (int cc = 0; cc < 2; ++cc)
#pragma unroll
        for (int n0 = 0; n0 < 4; ++n0) acc2[cc][n0] = (f32x4){0.f, 0.f, 0.f, 0.f};
#pragma unroll
    for (int n0 = 0; n0 < 4; ++n0) {
        const int o = (n0 * 16 + lm) * 64 + (lh << 3);
        bfrag8 bh0 = *(const bfrag8*)(const void*)&ahl[o];
        bfrag8 bh1 = *(const bfrag8*)(const void*)&ahl[o + 32];
        bfrag8 bl0 = *(const bfrag8*)(const void*)&ahl[4096 + o];
        bfrag8 bl1 = *(const bfrag8*)(const void*)&ahl[4096 + o + 32];
#pragma unroll
        for (int cc = 0; cc < 2; ++cc) {
            const int c = colw + cc * 16 + lm;
            bfrag8 a0 = *(const bfrag8*)(const void*)&xwt[c * 72 + (lh << 3)];
            bfrag8 a1 = *(const bfrag8*)(const void*)&xwt[c * 72 + 32 + (lh << 3)];
            acc2[cc][n0] = __builtin_amdgcn_mfma_f32_16x16x32_bf16(a0, bh0, acc2[cc][n0], 0, 0, 0);
            acc2[cc][n0] = __builtin_amdgcn_mfma_f32_16x16x32_bf16(a0, bl0, acc2[cc][n0], 0, 0, 0);
            acc2[cc][n0] = __builtin_amdgcn_mfma_f32_16x16x32_bf16(a1, bh1, acc2[cc][n0], 0, 0, 0);
            acc2[cc][n0] = __builtin_amdgcn_mfma_f32_16x16x32_bf16(a1, bl1, acc2[cc][n0], 0, 0, 0);
        }
    }

    // ---- bias + us4 writeback to cur + pool (shfl over lm) ----
#pragma unroll
    for (int cc = 0; cc < 2; ++cc) {
        const int cb = colw + cc * 16 + (lh << 2);   // 4 consecutive cols
        float bv[4];
#pragma unroll
        for (int r = 0; r < 4; ++r) {
            int c = cb + r;
            bv[r] = (c < HC) ? bias[c] : 0.f;
        }
        float t0 = 0.f, t1 = 0.f, t2 = 0.f, t3 = 0.f;
#pragma unroll
        for (int n0 = 0; n0 < 4; ++n0) {
            const int d = n0 * 16 + lm;              // node
            float v0 = acc2[cc][n0][0] + bv[0];
            float v1 = acc2[cc][n0][1] + bv[1];
            float v2 = acc2[cc][n0][2] + bv[2];
            float v3 = acc2[cc][n0][3] + bv[3];
            t0 += v0; t1 += v1; t2 += v2; t3 += v3;
            us4 p;
            p.a = f2b(v0); p.b = f2b(v1); p.c = f2b(v2); p.d = f2b(v3);
            *(us4*)(void*)&cur[d * 512 + (cb ^ ((d & 7) << 3))] = p;
        }
#pragma unroll
        for (int m = 1; m < 16; m <<= 1) {
            t0 += __shfl_xor(t0, m, 64);
            t1 += __shfl_xor(t1, m, 64);
            t2 += __shfl_xor(t2, m, 64);
            t3 += __shfl_xor(t3, m, 64);
        }
        if (lm == 0 && cb < HC)
            *(float4*)&hsg[cb] = make_float4(t0 * (1.0f / 64.0f), t1 * (1.0f / 64.0f),
                                             t2 * (1.0f / 64.0f), t3 * (1.0f / 64.0f));
    }
    __syncthreads();   // cur complete before next layer's feature reads
}

// ---------------------------------------------------------------------------
// Whole-GCN mega-kernel: one block = one graph, 16 waves, all 4 layers in LDS.
// ---------------------------------------------------------------------------
__global__ __launch_bounds__(1024, 4) void gcn_all(const float* __restrict__ x,
                                                   const int* __restrict__ esrc,
                                                   const int* __restrict__ edst,
                                                   const unsigned short* __restrict__ Wt0,
                                                   const unsigned short* __restrict__ Wt123,
                                                   const float* __restrict__ bg0,
                                                   const float* __restrict__ bgR,
                                                   float* __restrict__ hs)
{
    extern __shared__ char lds[];
    unsigned short* cur = (unsigned short*)lds;                    // 65536 B
    unsigned short* xwt = (unsigned short*)(lds + 65536);          // 73728 B
    unsigned short* ahl = (unsigned short*)(lds + 65536 + 73728);  // 16384 B
    float* Af   = (float*)(lds + 65536);                           // scratch in xwt
    int*   cnt  = (int*)(lds + 65536 + 16384);
    float* dinv = (float*)(lds + 65536 + 16384 + 256);

    const int g = blockIdx.x, tid = threadIdx.x;
    const int wv = tid >> 6, lane = tid & 63;
    const int lm = lane & 15, lh = lane >> 4;

    // ---- build normalized adjacency in LDS ----
    for (int i = tid; i < 4096; i += 1024) Af[i] = 0.f;
    if (tid < 64) cnt[tid] = 0;
    __syncthreads();
    atomicAdd(&cnt[edst[(size_t)g * EPER + tid] & 63], 1);
    __syncthreads();
    if (tid < 64) dinv[tid] = rsqrtf((float)cnt[tid] + 1.0f);
    __syncthreads();
    {
        int s = esrc[(size_t)g * EPER + tid] & 63;
        int d = edst[(size_t)g * EPER + tid] & 63;
        atomicAdd(&Af[d * 64 + s], dinv[s] * dinv[d]);
    }
    __syncthreads();
    if (tid < 64) Af[tid * 64 + tid] += dinv[tid] * dinv[tid];
    __syncthreads();
    for (int i = tid; i < 4096; i += 1024) {
        float v = Af[i];
        unsigned short h = f2b(v);
        ahl[i] = h;
        ahl[4096 + i] = f2b(v - b2f(h));
    }
    // ---- load x -> cur (bf16, swizzled); layer0 uses k<64 only ----
    {
        float4 v = ((const float4*)(x + (size_t)g * 4096))[tid];
        int row = (tid * 4) >> 6, col = (tid * 4) & 63;
        unsigned short* p = &cur[row * 512 + (col ^ ((row & 7) << 3))];
        p[0] = f2b(v.x); p[1] = f2b(v.y); p[2] = f2b(v.z); p[3] = f2b(v.w);
    }
    __syncthreads();

    float* hsg = hs + (size_t)g * (HC * NLAY);
    gcn_layer<64>(Wt0, bg0, cur, xwt, ahl, hsg, wv, lm, lh);
    for (int l = 1; l < NLAY; ++l)
        gcn_layer<512>(Wt123 + (size_t)(l - 1) * 262144, bgR + (l - 1) * HC,
                       cur, xwt, ahl, hsg + l * HC, wv, lm, lh);
}

// ---------------------------------------------------------------------------
// BN statistics, stage 1: partial sums over a row block (coalesced).
// ---------------------------------------------------------------------------
__global__ __launch_bounds__(256) void stats_part(const float* __restrict__ in,
                                                  float* __restrict__ ps,
                                                  float* __restrict__ pss,
                                                  int F, int rpb)
{
    int f = blockIdx.x * 256 + threadIdx.x;
    if (f >= F) return;
    int r0 = blockIdx.y * rpb;
    float s = 0.f, ss = 0.f;
    for (int r = r0; r < r0 + rpb; ++r) {
        float v = in[(size_t)r * F + f];
        s += v; ss += v * v;
    }
    ps [(size_t)blockIdx.y * F + f] = s;
    pss[(size_t)blockIdx.y * F + f] = ss;
}

// ---------------------------------------------------------------------------
// BN statistics, stage 2: reduce GB partials -> mean, rsqrt(var+eps)
// ---------------------------------------------------------------------------
__global__ __launch_bounds__(256) void stats_fin(const float* __restrict__ ps,
                                                 const float* __restrict__ pss,
                                                 float* __restrict__ mean,
                                                 float* __restrict__ inv,
                                                 int F, int GB, float invR)
{
    int f = blockIdx.x * 256 + threadIdx.x;
    if (f >= F) return;
    float s = 0.f, ss = 0.f;
    for (int b = 0; b < GB; ++b) { s += ps[(size_t)b * F + f]; ss += pss[(size_t)b * F + f]; }
    float m = s * invR;
    mean[f] = m;
    inv[f]  = rsqrtf(ss * invR - m * m + 1e-5f);
}

// ---------------------------------------------------------------------------
// Gather triu entries of x into xv[g][t] + partial stats over 16 graphs.
// triu index computed in closed form (no table).
// ---------------------------------------------------------------------------
__global__ __launch_bounds__(256) void xv_gather(const float* __restrict__ x,
                                                 float* __restrict__ xv,
                                                 float* __restrict__ ps,
                                                 float* __restrict__ pss)
{
    int t = blockIdx.x * 256 + threadIdx.x;
    if (t >= NTRIU) return;
    int i = (int)(63.5f - sqrtf(63.5f * 63.5f - 2.0f * (float)t));
    while (63 * (i + 1) - (i + 1) * i / 2 <= t) ++i;
    while (63 * i - i * (i - 1) / 2 > t) --i;
    int j = t - (63 * i - i * (i - 1) / 2) + i + 1;
    int o = i * 64 + j;
    int g0 = blockIdx.y * 16;
    float s = 0.f, ss = 0.f;
    for (int g = g0; g < g0 + 16; ++g) {
        float v = x[(size_t)g * 4096 + o];
        xv[(size_t)g * NTRIU + t] = v;
        s += v; ss += v * v;
    }
    ps [(size_t)blockIdx.y * NTRIU + t] = s;
    pss[(size_t)blockIdx.y * NTRIU + t] = ss;
}

// ---------------------------------------------------------------------------
// Fused: normalize xv & hs inline, attention dot, sigmoid, write z as
// split-bf16 (hi/lo) planes. One block per graph.
// ---------------------------------------------------------------------------
__global__ __launch_bounds__(256) void attz_fused(const float* __restrict__ xv,
                                                  const float* __restrict__ xm,
                                                  const float* __restrict__ xi,
                                                  const float* __restrict__ gx,
                                                  const float* __restrict__ bx,
                                                  const float* __restrict__ hsrc,
                                                  const float* __restrict__ hm,
                                                  const float* __restrict__ hi,
                                                  const float* __restrict__ gh,
                                                  const float* __restrict__ bh,
                                                  const float* __restrict__ Watt,
                                                  const float* __restrict__ batt,
                                                  unsigned short* __restrict__ zhi,
                                                  unsigned short* __restrict__ zlo)
{
    int g = blockIdx.x;
    __shared__ float xs[NTRIU];
    __shared__ float red[256];
    float s = 0.f;
    for (int t = threadIdx.x; t < NTRIU; t += 256) {
        float v = (xv[(size_t)g * NTRIU + t] - xm[t]) * xi[t] * gx[t] + bx[t];
        xs[t] = v;
        s += v * Watt[t];
    }
    red[threadIdx.x] = s;
    __syncthreads();
    for (int w = 128; w > 0; w >>= 1) {
        if (threadIdx.x < w) red[threadIdx.x] += red[threadIdx.x + w];
        __syncthreads();
    }
    float att = 1.0f / (1.0f + expf(-(red[0] + batt[0])));
    for (int t = threadIdx.x; t < NTRIU; t += 256) {
        float hn = (hsrc[(size_t)g * NTRIU + t] - hm[t]) * hi[t] * gh[t] + bh[t];
        float zf = att * xs[t] + (1.0f - att) * hn * 0.5f;
        unsigned short h0 = f2b(zf);
        zhi[(size_t)g * DCAT + t] = h0;
        zlo[(size_t)g * DCAT + t] = f2b(zf - b2f(h0));
        unsigned short h1 = f2b(hn);
        zhi[(size_t)g * DCAT + NTRIU + t] = h1;
        zlo[(size_t)g * DCAT + NTRIU + t] = f2b(hn - b2f(h1));
    }
}

// ---------------------------------------------------------------------------
// Split-K bf16 MFMA GEMM with hi/lo-split A:
// P[z][256][N] partial = (Ahi+Alo)[256][K-chunk] @ Bt[N][K]^T
// ---------------------------------------------------------------------------
__global__ __launch_bounds__(256) void gemm_bf_sk(const unsigned short* __restrict__ Ahi,
                                                  const unsigned short* __restrict__ Alo,
                                                  const unsigned short* __restrict__ Bt,
                                                  float* __restrict__ P,
                                                  int N, int K, int chunk)
{
    __shared__ unsigned short Ah[2][2048], Al[2][2048], Bs[2][2048];
    const int tid  = threadIdx.x;
    const int wave = tid >> 6, lane = tid & 63;
    const int row0 = blockIdx.y << 6, col0 = blockIdx.x << 6;
    const int kb = blockIdx.z * chunk;
    const int NT = chunk >> 5;
    const int sr = tid >> 2, sk = (tid & 3) << 3;
    const unsigned short* gAh = Ahi + (size_t)(row0 + sr) * K + kb + sk;
    const unsigned short* gAl = Alo + (size_t)(row0 + sr) * K + kb + sk;
    const unsigned short* gB  = Bt  + (size_t)(col0 + sr) * K + kb + sk;

    int4 rh = *(const int4*)(const void*)gAh;
    int4 rl = *(const int4*)(const void*)gAl;
    int4 rb = *(const int4*)(const void*)gB;
    *(int4*)(void*)&Ah[0][tid << 3] = rh;
    *(int4*)(void*)&Al[0][tid << 3] = rl;
    *(int4*)(void*)&Bs[0][tid << 3] = rb;
    __syncthreads();

    f32x4 acc0 = {0.f, 0.f, 0.f, 0.f};
    f32x4 acc1 = acc0, acc2 = acc0, acc3 = acc0;
    const int aoff = (wave * 16 + (lane & 15)) * 32 + ((lane >> 4) << 3);
    const int boff = (lane & 15) * 32 + ((lane >> 4) << 3);

    for (int t = 0; t < NT; ++t) {
        if (t + 1 < NT) {
            rh = *(const int4*)(const void*)(gAh + (t + 1) * 32);
            rl = *(const int4*)(const void*)(gAl + (t + 1) * 32);
            rb = *(const int4*)(const void*)(gB  + (t + 1) * 32);
        }
        const unsigned short* ah = Ah[t & 1];
        const unsigned short* al = Al[t & 1];
        const unsigned short* bs = Bs[t & 1];
        bfrag8 a  = *(const bfrag8*)(const void*)&ah[aoff];
        bfrag8 a2 = *(const bfrag8*)(const void*)&al[aoff];
        bfrag8 b0 = *(const bfrag8*)(const void*)&bs[boff];
        bfrag8 b1 = *(const bfrag8*)(const void*)&bs[boff + 16 * 32];
        bfrag8 b2 = *(const bfrag8*)(const void*)&bs[boff + 32 * 32];
        bfrag8 b3 = *(const bfrag8*)(const void*)&bs[boff + 48 * 32];
        acc0 = __builtin_amdgcn_mfma_f32_16x16x32_bf16(a,  b0, acc0, 0, 0, 0);
        acc0 = __builtin_amdgcn_mfma_f32_16x16x32_bf16(a2, b0, acc0, 0, 0, 0);
        acc1 = __builtin_amdgcn_mfma_f32_16x16x32_bf16(a,  b1, acc1, 0, 0, 0);
        acc1 = __builtin_amdgcn_mfma_f32_16x16x32_bf16(a2, b1, acc1, 0, 0, 0);
        acc2 = __builtin_amdgcn_mfma_f32_16x16x32_bf16(a,  b2, acc2, 0, 0, 0);
        acc2 = __builtin_amdgcn_mfma_f32_16x16x32_bf16(a2, b2, acc2, 0, 0, 0);
        acc3 = __builtin_amdgcn_mfma_f32_16x16x32_bf16(a,  b3, acc3, 0, 0, 0);
        acc3 = __builtin_amdgcn_mfma_f32_16x16x32_bf16(a2, b3, acc3, 0, 0, 0);
        if (t + 1 < NT) {
            *(int4*)(void*)&Ah[(t + 1) & 1][tid << 3] = rh;
            *(int4*)(void*)&Al[(t + 1) & 1][tid << 3] = rl;
            *(int4*)(void*)&Bs[(t + 1) & 1][tid << 3] = rb;
        }
        __syncthreads();
    }

    float* Pp = P + (size_t)blockIdx.z * NGRAPH * N;
    const int rbase = row0 + wave * 16 + ((lane >> 4) << 2);
    const int cbase = col0 + (lane & 15);
#pragma unroll
    for (int r = 0; r < 4; ++r) {
        int grow = rbase + r;
        Pp[(size_t)grow * N + cbase +  0] = acc0[r];
        Pp[(size_t)grow * N + cbase + 16] = acc1[r];
        Pp[(size_t)grow * N + cbase + 32] = acc2[r];
        Pp[(size_t)grow * N + cbase + 48] = acc3[r];
    }
}

// ---------------------------------------------------------------------------
// Fused split-K reduce + bias -> mf, with BN partial stats (8-row groups).
// grid (N/256, 32).
// ---------------------------------------------------------------------------
__global__ __launch_bounds__(256) void reduce_stats(const float* __restrict__ P,
                                                    const float* __restrict__ bias,
                                                    float* __restrict__ mf,
                                                    float* __restrict__ ps,
                                                    float* __restrict__ pss,
                                                    int N, int S)
{
    int f = blockIdx.x * 256 + threadIdx.x;
    int r0 = blockIdx.y * 8;
    size_t MN = (size_t)NGRAPH * N;
    float bv = bias[f];
    float s = 0.f, ss = 0.f;
    for (int r = r0; r < r0 + 8; ++r) {
        float v = 0.f;
        for (int t = 0; t < S; ++t) v += P[(size_t)t * MN + (size_t)r * N + f];
        v += bv;
        mf[(size_t)r * N + f] = v;
        s += v; ss += v * v;
    }
    ps [(size_t)blockIdx.y * N + f] = s;
    pss[(size_t)blockIdx.y * N + f] = ss;
}

// ---------------------------------------------------------------------------
// BN apply + ReLU -> split-bf16 hi/lo planes.
// ---------------------------------------------------------------------------
__global__ __launch_bounds__(256) void bn_apply_bf(const float* __restrict__ M_,
                                                   const float* __restrict__ mean,
                                                   const float* __restrict__ inv,
                                                   const float* __restrict__ gamma,
                                                   const float* __restrict__ beta,
                                                   unsigned short* __restrict__ hi,
                                                   unsigned short* __restrict__ lo,
                                                   int total, int mask)
{
    int i = blockIdx.x * 256 + threadIdx.x;
    if (i >= total) return;
    int f = i & mask;
    float v = (M_[i] - mean[f]) * inv[f] * gamma[f] + beta[f];
    v = fmaxf(v, 0.f);
    unsigned short h = f2b(v);
    hi[i] = h;
    lo[i] = f2b(v - b2f(h));
}

// ---------------------------------------------------------------------------
// Final tiny linear from hi/lo bf16: out[g][0:2] = m3[g] @ Wm4 + bm4
// ---------------------------------------------------------------------------
__global__ __launch_bounds__(256) void final_kernel(const unsigned short* __restrict__ Xhi,
                                                    const unsigned short* __restrict__ Xlo,
                                                    const float* __restrict__ W,
                                                    const float* __restrict__ b,
                                                    float* __restrict__ out)
{
    int g = blockIdx.x;
    float s0 = 0.f, s1 = 0.f;
    for (int k = threadIdx.x; k < HID2; k += 256) {
        float v = b2f(Xhi[(size_t)g * HID2 + k]) + b2f(Xlo[(size_t)g * HID2 + k]);
        s0 += v * W[k * 2 + 0];
        s1 += v * W[k * 2 + 1];
    }
    __shared__ float r0[256], r1[256];
    r0[threadIdx.x] = s0; r1[threadIdx.x] = s1;
    __syncthreads();
    for (int w = 128; w > 0; w >>= 1) {
        if (threadIdx.x < w) {
            r0[threadIdx.x] += r0[threadIdx.x + w];
            r1[threadIdx.x] += r1[threadIdx.x + w];
        }
        __syncthreads();
    }
    if (threadIdx.x == 0) {
        out[g * 2 + 0] = r0[0] + b[0];
        out[g * 2 + 1] = r1[0] + b[1];
    }
}

// ---------------------------------------------------------------------------
extern "C" void kernel_launch(void* const* d_in, const int* in_sizes, int n_in,
                              void* d_out, int out_size, void* d_ws, size_t ws_size,
                              hipStream_t stream)
{
    const float* x      = (const float*)d_in[0];
    const float* Wg0    = (const float*)d_in[1];
    const float* bg0    = (const float*)d_in[2];
    const float* WgR    = (const float*)d_in[3];
    const float* bgR    = (const float*)d_in[4];
    const float* gx     = (const float*)d_in[5];
    const float* bx     = (const float*)d_in[6];
    const float* gh     = (const float*)d_in[7];
    const float* bh     = (const float*)d_in[8];
    const float* Watt   = (const float*)d_in[9];
    const float* batt   = (const float*)d_in[10];
    const float* Wm1    = (const float*)d_in[11];
    const float* bm1    = (const float*)d_in[12];
    const float* gm1    = (const float*)d_in[13];
    const float* bem1   = (const float*)d_in[14];
    const float* Wm2    = (const float*)d_in[15];
    const float* bm2    = (const float*)d_in[16];
    const float* gm2    = (const float*)d_in[17];
    const float* bem2   = (const float*)d_in[18];
    const float* Wm3    = (const float*)d_in[19];
    const float* bm3    = (const float*)d_in[20];
    const float* gm3    = (const float*)d_in[21];
    const float* bem3   = (const float*)d_in[22];
    const float* Wm4    = (const float*)d_in[23];
    const float* bm4    = (const float*)d_in[24];
    const int*   esrc   = (const int*)d_in[25];
    const int*   edst   = (const int*)d_in[26];
    float* out = (float*)d_out;

    char* w = (char*)d_ws;
    auto alloc = [&](size_t bytes) -> char* {
        char* p = w;
        w += (bytes + 255) & ~(size_t)255;
        return p;
    };
    unsigned short* Wt0   = (unsigned short*)alloc((size_t)512 * 64 * 2);
    unsigned short* Wt123 = (unsigned short*)alloc((size_t)3 * 512 * 512 * 2);
    unsigned short* W1t   = (unsigned short*)alloc((size_t)HID1 * DCAT * 2);
    unsigned short* W2t   = (unsigned short*)alloc((size_t)HID2 * HID1 * 2);
    unsigned short* W3t   = (unsigned short*)alloc((size_t)HID2 * HID2 * 2);
    float*          hs    = (float*)alloc((size_t)NGRAPH * NTRIU * 4);
    float*          xv    = (float*)alloc((size_t)NGRAPH * NTRIU * 4);
    unsigned short* zhi   = (unsigned short*)alloc((size_t)NGRAPH * DCAT * 2);
    unsigned short* zlo   = (unsigned short*)alloc((size_t)NGRAPH * DCAT * 2);
    float*          P     = (float*)alloc((size_t)8 * NGRAPH * HID1 * 4);
    float*          mf    = (float*)alloc((size_t)NGRAPH * HID1 * 4);
    unsigned short* m1hi  = (unsigned short*)alloc((size_t)NGRAPH * HID1 * 2);
    unsigned short* m1lo  = (unsigned short*)alloc((size_t)NGRAPH * HID1 * 2);
    unsigned short* m2hi  = (unsigned short*)alloc((size_t)NGRAPH * HID2 * 2);
    unsigned short* m2lo  = (unsigned short*)alloc((size_t)NGRAPH * HID2 * 2);
    unsigned short* m3hi  = (unsigned short*)alloc((size_t)NGRAPH * HID2 * 2);
    unsigned short* m3lo  = (unsigned short*)alloc((size_t)NGRAPH * HID2 * 2);
    float*          ps    = (float*)alloc((size_t)32 * NTRIU * 4);
    float*          pss   = (float*)alloc((size_t)32 * NTRIU * 4);
    float*          xm    = (float*)alloc(NTRIU * 4);
    float*          xi    = (float*)alloc(NTRIU * 4);
    float*          hm    = (float*)alloc(NTRIU * 4);
    float*          hiv   = (float*)alloc(NTRIU * 4);
    float*          mmean = (float*)alloc(HID1 * 4);
    float*          minv  = (float*)alloc(HID1 * 4);

    hipFuncSetAttribute((const void*)gcn_all,
                        hipFuncAttributeMaxDynamicSharedMemorySize, GCN_LDS);

    convW4<<<dim3(16, 2, 1),   dim3(32, 8), 0, stream>>>(Wg0, Wt0, 64, HC, 64, 0, 0);
    convW4<<<dim3(16, 16, 3),  dim3(32, 8), 0, stream>>>(WgR, Wt123, HC, HC, 512,
                                                         (long long)HC * HC, 512LL * 512);
    convWt<<<dim3(32, 126, 1), dim3(32, 8), 0, stream>>>(Wm1, W1t, DCAT, HID1, DCAT, 0, 0);
    convWt<<<dim3(16, 32, 1),  dim3(32, 8), 0, stream>>>(Wm2, W2t, HID1, HID2, HID1, 0, 0);
    convWt<<<dim3(16, 16, 1),  dim3(32, 8), 0, stream>>>(Wm3, W3t, HID2, HID2, HID2, 0, 0);

    // Whole GCN (adjacency build + 4 layers + pool) in one kernel, 16 waves
    gcn_all<<<NGRAPH, 1024, GCN_LDS, stream>>>(x, esrc, edst, Wt0, Wt123, bg0, bgR, hs);

    // BN stats for h and xv, fused attention + z (split-bf16)
    stats_part<<<dim3(8, 16), 256, 0, stream>>>(hs, ps, pss, NTRIU, 16);
    stats_fin<<<8, 256, 0, stream>>>(ps, pss, hm, hiv, NTRIU, 16, 1.0f / NGRAPH);
    xv_gather<<<dim3(8, 16), 256, 0, stream>>>(x, xv, ps, pss);
    stats_fin<<<8, 256, 0, stream>>>(ps, pss, xm, xi, NTRIU, 16, 1.0f / NGRAPH);
    attz_fused<<<NGRAPH, 256, 0, stream>>>(xv, xm, xi, gx, bx, hs, hm, hiv, gh, bh,
                                           Watt, batt, zhi, zlo);

    // MLP layer 1: [256,4032] @ [4032,1024]
    gemm_bf_sk<<<dim3(16, 4, 7), 256, 0, stream>>>(zhi, zlo, W1t, P, HID1, DCAT, 576);
    reduce_stats<<<dim3(4, 32), 256, 0, stream>>>(P, bm1, mf, ps, pss, HID1, 7);
    stats_fin<<<4, 256, 0, stream>>>(ps, pss, mmean, minv, HID1, 32, 1.0f / NGRAPH);
    bn_apply_bf<<<1024, 256, 0, stream>>>(mf, mmean, minv, gm1, bem1, m1hi, m1lo,
                                          NGRAPH * HID1, HID1 - 1);

    // MLP layer 2: [256,1024] @ [1024,512]
    gemm_bf_sk<<<dim3(8, 4, 8), 256, 0, stream>>>(m1hi, m1lo, W2t, P, HID2, HID1, 128);
    reduce_stats<<<dim3(2, 32), 256, 0, stream>>>(P, bm2, mf, ps, pss, HID2, 8);
    stats_fin<<<2, 256, 0, stream>>>(ps, pss, mmean, minv, HID2, 32, 1.0f / NGRAPH);
    bn_apply_bf<<<512, 256, 0, stream>>>(mf, mmean, minv, gm2, bem2, m2hi, m2lo,
                                         NGRAPH * HID2, HID2 - 1);

    // MLP layer 3: [256,512] @ [512,512]
    gemm_bf_sk<<<dim3(8, 4, 8), 256, 0, stream>>>(m2hi, m2lo, W3t, P, HID2, HID2, 64);
    reduce_stats<<<dim3(2, 32), 256, 0, stream>>>(P, bm3, mf, ps, pss, HID2, 8);
    stats_fin<<<2, 256, 0, stream>>>(ps, pss, mmean, minv, HID2, 32, 1.0f / NGRAPH);
    bn_apply_bf<<<512, 256, 0, stream>>>(mf, mmean, minv, gm3, bem3, m3hi, m3lo,
                                         NGRAPH * HID2, HID2 - 1);

    final_kernel<<<NGRAPH, 256, 0, stream>>>(m3hi, m3lo, Wm4, bm4, out);
}

// Round 9
// 186.302 us; speedup vs baseline: 1.0910x; 1.0910x over previous
//
#include <hip/hip_runtime.h>
#include <math.h>

#define NGRAPH 256
#define NPG 64
#define NFEAT 64
#define HC 504
#define NLAY 4
#define EPER 1024
#define NTRIU 2016
#define DCAT 4032
#define HID1 1024
#define HID2 512

// cur 65536 + xwt 73728 + ahl(2 planes, pitch 72) 18432 = 157696 B <= 160KiB
#define GCN_LDS (65536 + 73728 + 18432)
#define AHL_LO 4608   // 64*72 elements: offset of lo plane

typedef __attribute__((ext_vector_type(8))) short bfrag8;   // 8 bf16 in 4 VGPRs
typedef __attribute__((ext_vector_type(4))) float f32x4;

struct __align__(8) us4 { unsigned short a, b, c, d; };

__device__ __forceinline__ unsigned short f2b(float f) {
    union { float f; unsigned u; } v; v.f = f;
    unsigned r = (v.u + 0x7fffu + ((v.u >> 16) & 1u)) >> 16;   // RNE
    return (unsigned short)r;
}
__device__ __forceinline__ float b2f(unsigned short h) {
    union { unsigned u; float f; } v; v.u = ((unsigned)h) << 16;
    return v.f;
}

// ---------------------------------------------------------------------------
// Weight transpose+convert (row layout): Wt[n][k] = bf16(W[k][n])
// ---------------------------------------------------------------------------
__global__ void convWt(const float* __restrict__ W, unsigned short* __restrict__ Wt,
                       int K, int N, int KP, long long sStride, long long dStride)
{
    W  += (size_t)blockIdx.z * sStride;
    Wt += (size_t)blockIdx.z * dStride;
    __shared__ float T[32][33];
    int k0 = blockIdx.y * 32, n0 = blockIdx.x * 32;
    int tx = threadIdx.x, ty = threadIdx.y;
#pragma unroll
    for (int j = 0; j < 32; j += 8) {
        int k = k0 + ty + j, n = n0 + tx;
        T[ty + j][tx] = (k < K && n < N) ? W[(size_t)k * N + n] : 0.f;
    }
    __syncthreads();
#pragma unroll
    for (int j = 0; j < 32; j += 8) {
        int n = n0 + ty + j, k = k0 + tx;
        Wt[(size_t)n * KP + k] = f2b(T[tx][ty + j]);
    }
}

// ---------------------------------------------------------------------------
// Weight convert to MFMA-fragment-major layout (for gcn_all):
// elem (n,k) -> ((n>>4)*(KL/32) + (k>>5))*512 + ((k>>3)&3)*128 + (n&15)*8 + (k&7)
// ---------------------------------------------------------------------------
__global__ void convW4(const float* __restrict__ W, unsigned short* __restrict__ W4,
                       int K, int N, int KL, long long sStride, long long dStride)
{
    W  += (size_t)blockIdx.z * sStride;
    W4 += (size_t)blockIdx.z * dStride;
    __shared__ float T[32][33];
    int k0 = blockIdx.y * 32, n0 = blockIdx.x * 32;
    int tx = threadIdx.x, ty = threadIdx.y;
#pragma unroll
    for (int j = 0; j < 32; j += 8) {
        int k = k0 + ty + j, n = n0 + tx;
        T[ty + j][tx] = (k < K && n < N) ? W[(size_t)k * N + n] : 0.f;
    }
    __syncthreads();
#pragma unroll
    for (int j = 0; j < 32; j += 8) {
        int n = n0 + ty + j, k = k0 + tx;
        int idx = ((n >> 4) * (KL >> 5) + (k >> 5)) * 512
                + (((k >> 3) & 3) << 7) + ((n & 15) << 3) + (k & 7);
        W4[idx] = f2b(T[tx][ty + j]);
    }
}

// ---------------------------------------------------------------------------
// One GCN layer, one graph, 16 waves: wave wv owns 32 cols [wv*32, wv*32+32).
// ahl pitch = 72 elements (144B rows) -> adjacency ds_read_b128 conflict-free.
// ---------------------------------------------------------------------------
template<int KL>
__device__ __forceinline__ void gcn_layer(const unsigned short* __restrict__ W4,
                                          const float* __restrict__ bias,
                                          unsigned short* cur, unsigned short* xwt,
                                          const unsigned short* ahl,
                                          float* __restrict__ hsg,
                                          int wv, int lm, int lh)
{
    constexpr int KTS = KL >> 5;
    const int colw = wv << 5;             // 32 cols per wave
    const int kswz = (lm & 7) << 3;
    const int lane8 = ((lh << 4) + lm) << 3;   // lane * 8

    f32x4 acc[4][2];
#pragma unroll
    for (int m0 = 0; m0 < 4; ++m0)
#pragma unroll
        for (int cc = 0; cc < 2; ++cc) acc[m0][cc] = (f32x4){0.f, 0.f, 0.f, 0.f};

    // ---- phase 1: feature GEMM with depth-2 weight prefetch ----
    bfrag8 bq[2][2];
#pragma unroll
    for (int cc = 0; cc < 2; ++cc)
        bq[0][cc] = *(const bfrag8*)(const void*)&W4[(size_t)((wv * 2 + cc) * KTS + 0) * 512 + lane8];
    if (KTS > 1) {
#pragma unroll
        for (int cc = 0; cc < 2; ++cc)
            bq[1][cc] = *(const bfrag8*)(const void*)&W4[(size_t)((wv * 2 + cc) * KTS + 1) * 512 + lane8];
    }
#pragma unroll
    for (int kt = 0; kt < KTS; ++kt) {
        bfrag8 a[4];
#pragma unroll
        for (int m0 = 0; m0 < 4; ++m0)
            a[m0] = *(const bfrag8*)(const void*)&cur[(m0 * 16 + lm) * 512 + ((kt * 32 + (lh << 3)) ^ kswz)];
        bfrag8 bc[2];
        bc[0] = bq[kt & 1][0]; bc[1] = bq[kt & 1][1];
        if (kt + 2 < KTS) {
#pragma unroll
            for (int cc = 0; cc < 2; ++cc)
                bq[kt & 1][cc] = *(const bfrag8*)(const void*)&W4[(size_t)((wv * 2 + cc) * KTS + kt + 2) * 512 + lane8];
        }
#pragma unroll
        for (int cc = 0; cc < 2; ++cc)
#pragma unroll
            for (int m0 = 0; m0 < 4; ++m0)
                acc[m0][cc] = __builtin_amdgcn_mfma_f32_16x16x32_bf16(a[m0], bc[cc], acc[m0][cc], 0, 0, 0);
    }
    __syncthreads();   // all waves' cur reads complete before epilogue rewrites cur

    // ---- write XW^T to wave-private xwt cols (us4; no barrier needed) ----
#pragma unroll
    for (int cc = 0; cc < 2; ++cc) {
        const int c = colw + cc * 16 + lm;
#pragma unroll
        for (int m0 = 0; m0 < 4; ++m0) {
            us4 p;
            p.a = f2b(acc[m0][cc][0]); p.b = f2b(acc[m0][cc][1]);
            p.c = f2b(acc[m0][cc][2]); p.d = f2b(acc[m0][cc][3]);
            *(us4*)(void*)&xwt[c * 72 + m0 * 16 + (lh << 2)] = p;
        }
    }

    // ---- phase 2 (swapped): acc2[cc][n0] = Y^T tile ----
    f32x4 acc2[2][4];
#pragma unroll
    for (int cc = 0; cc < 2; ++cc)
#pragma unroll
        for (int n0 = 0; n0 < 4; ++n0) acc2[cc][n0] = (f32x4){0.f, 0.f, 0.f, 0.f};
#pragma unroll
    for (int n0 = 0; n0 < 4; ++n0) {
        const int o = (n0 * 16 + lm) * 72 + (lh << 3);   // pitch 72: conflict-free
        bfrag8 bh0 = *(const bfrag8*)(const void*)&ahl[o];
        bfrag8 bh1 = *(const bfrag8*)(const void*)&ahl[o + 32];
        bfrag8 bl0 = *(const bfrag8*)(const void*)&ahl[AHL_LO + o];
        bfrag8 bl1 = *(const bfrag8*)(const void*)&ahl[AHL_LO + o + 32];
#pragma unroll
        for (int cc = 0; cc < 2; ++cc) {
            const int c = colw + cc * 16 + lm;
            bfrag8 a0 = *(const bfrag8*)(const void*)&xwt[c * 72 + (lh << 3)];
            bfrag8 a1 = *(const bfrag8*)(const void*)&xwt[c * 72 + 32 + (lh << 3)];
            acc2[cc][n0] = __builtin_amdgcn_mfma_f32_16x16x32_bf16(a0, bh0, acc2[cc][n0], 0, 0, 0);
            acc2[cc][n0] = __builtin_amdgcn_mfma_f32_16x16x32_bf16(a0, bl0, acc2[cc][n0], 0, 0, 0);
            acc2[cc][n0] = __builtin_amdgcn_mfma_f32_16x16x32_bf16(a1, bh1, acc2[cc][n0], 0, 0, 0);
            acc2[cc][n0] = __builtin_amdgcn_mfma_f32_16x16x32_bf16(a1, bl1, acc2[cc][n0], 0, 0, 0);
        }
    }

    // ---- bias + us4 writeback to cur + pool (shfl over lm) ----
#pragma unroll
    for (int cc = 0; cc < 2; ++cc) {
        const int cb = colw + cc * 16 + (lh << 2);   // 4 consecutive cols
        float bv[4];
#pragma unroll
        for (int r = 0; r < 4; ++r) {
            int c = cb + r;
            bv[r] = (c < HC) ? bias[c] : 0.f;
        }
        float t0 = 0.f, t1 = 0.f, t2 = 0.f, t3 = 0.f;
#pragma unroll
        for (int n0 = 0; n0 < 4; ++n0) {
            const int d = n0 * 16 + lm;              // node
            float v0 = acc2[cc][n0][0] + bv[0];
            float v1 = acc2[cc][n0][1] + bv[1];
            float v2 = acc2[cc][n0][2] + bv[2];
            float v3 = acc2[cc][n0][3] + bv[3];
            t0 += v0; t1 += v1; t2 += v2; t3 += v3;
            us4 p;
            p.a = f2b(v0); p.b = f2b(v1); p.c = f2b(v2); p.d = f2b(v3);
            *(us4*)(void*)&cur[d * 512 + (cb ^ ((d & 7) << 3))] = p;
        }
#pragma unroll
        for (int m = 1; m < 16; m <<= 1) {
            t0 += __shfl_xor(t0, m, 64);
            t1 += __shfl_xor(t1, m, 64);
            t2 += __shfl_xor(t2, m, 64);
            t3 += __shfl_xor(t3, m, 64);
        }
        if (lm == 0 && cb < HC)
            *(float4*)&hsg[cb] = make_float4(t0 * (1.0f / 64.0f), t1 * (1.0f / 64.0f),
                                             t2 * (1.0f / 64.0f), t3 * (1.0f / 64.0f));
    }
    __syncthreads();   // cur complete before next layer's feature reads
}

// ---------------------------------------------------------------------------
// Whole-GCN mega-kernel: one block = one graph, 16 waves, all 4 layers in LDS.
// ---------------------------------------------------------------------------
__global__ __launch_bounds__(1024, 4) void gcn_all(const float* __restrict__ x,
                                                   const int* __restrict__ esrc,
                                                   const int* __restrict__ edst,
                                                   const unsigned short* __restrict__ Wt0,
                                                   const unsigned short* __restrict__ Wt123,
                                                   const float* __restrict__ bg0,
                                                   const float* __restrict__ bgR,
                                                   float* __restrict__ hs)
{
    extern __shared__ char lds[];
    unsigned short* cur = (unsigned short*)lds;                    // 65536 B
    unsigned short* xwt = (unsigned short*)(lds + 65536);          // 73728 B
    unsigned short* ahl = (unsigned short*)(lds + 65536 + 73728);  // 18432 B (pitch 72)
    float* Af   = (float*)(lds + 65536);                           // scratch in xwt
    int*   cnt  = (int*)(lds + 65536 + 16384);
    float* dinv = (float*)(lds + 65536 + 16384 + 256);

    const int g = blockIdx.x, tid = threadIdx.x;
    const int wv = tid >> 6, lane = tid & 63;
    const int lm = lane & 15, lh = lane >> 4;

    // ---- build normalized adjacency in LDS ----
    for (int i = tid; i < 4096; i += 1024) Af[i] = 0.f;
    if (tid < 64) cnt[tid] = 0;
    __syncthreads();
    atomicAdd(&cnt[edst[(size_t)g * EPER + tid] & 63], 1);
    __syncthreads();
    if (tid < 64) dinv[tid] = rsqrtf((float)cnt[tid] + 1.0f);
    __syncthreads();
    {
        int s = esrc[(size_t)g * EPER + tid] & 63;
        int d = edst[(size_t)g * EPER + tid] & 63;
        atomicAdd(&Af[d * 64 + s], dinv[s] * dinv[d]);
    }
    __syncthreads();
    if (tid < 64) Af[tid * 64 + tid] += dinv[tid] * dinv[tid];
    __syncthreads();
    for (int i = tid; i < 4096; i += 1024) {
        float v = Af[i];
        unsigned short h = f2b(v);
        int d = i >> 6, s = i & 63;
        ahl[d * 72 + s] = h;
        ahl[AHL_LO + d * 72 + s] = f2b(v - b2f(h));
    }
    // ---- load x -> cur (bf16, swizzled); layer0 uses k<64 only ----
    {
        float4 v = ((const float4*)(x + (size_t)g * 4096))[tid];
        int row = (tid * 4) >> 6, col = (tid * 4) & 63;
        unsigned short* p = &cur[row * 512 + (col ^ ((row & 7) << 3))];
        p[0] = f2b(v.x); p[1] = f2b(v.y); p[2] = f2b(v.z); p[3] = f2b(v.w);
    }
    __syncthreads();

    float* hsg = hs + (size_t)g * (HC * NLAY);
    gcn_layer<64>(Wt0, bg0, cur, xwt, ahl, hsg, wv, lm, lh);
    for (int l = 1; l < NLAY; ++l)
        gcn_layer<512>(Wt123 + (size_t)(l - 1) * 262144, bgR + (l - 1) * HC,
                       cur, xwt, ahl, hsg + l * HC, wv, lm, lh);
}

// ---------------------------------------------------------------------------
// Dual-job pre-BN kernel: z=0 -> hs partial stats; z=1 -> xv gather + stats.
// grid (8, 16, 2).
// ---------------------------------------------------------------------------
__global__ __launch_bounds__(256) void pre_stats(const float* __restrict__ hs,
                                                 const float* __restrict__ x,
                                                 float* __restrict__ xv,
                                                 float* __restrict__ psh,
                                                 float* __restrict__ pssh,
                                                 float* __restrict__ psx,
                                                 float* __restrict__ pssx)
{
    int t = blockIdx.x * 256 + threadIdx.x;
    if (t >= NTRIU) return;
    int g0 = blockIdx.y * 16;
    if (blockIdx.z == 0) {
        float s = 0.f, ss = 0.f;
        for (int g = g0; g < g0 + 16; ++g) {
            float v = hs[(size_t)g * NTRIU + t];
            s += v; ss += v * v;
        }
        psh [(size_t)blockIdx.y * NTRIU + t] = s;
        pssh[(size_t)blockIdx.y * NTRIU + t] = ss;
    } else {
        int i = (int)(63.5f - sqrtf(63.5f * 63.5f - 2.0f * (float)t));
        while (63 * (i + 1) - (i + 1) * i / 2 <= t) ++i;
        while (63 * i - i * (i - 1) / 2 > t) --i;
        int j = t - (63 * i - i * (i - 1) / 2) + i + 1;
        int o = i * 64 + j;
        float s = 0.f, ss = 0.f;
        for (int g = g0; g < g0 + 16; ++g) {
            float v = x[(size_t)g * 4096 + o];
            xv[(size_t)g * NTRIU + t] = v;
            s += v; ss += v * v;
        }
        psx [(size_t)blockIdx.y * NTRIU + t] = s;
        pssx[(size_t)blockIdx.y * NTRIU + t] = ss;
    }
}

// ---------------------------------------------------------------------------
// Dual stats finalize: y=0 -> (psh -> hm,hiv), y=1 -> (psx -> xm,xi). grid (8,2).
// ---------------------------------------------------------------------------
__global__ __launch_bounds__(256) void stats_fin2(const float* __restrict__ psh,
                                                  const float* __restrict__ pssh,
                                                  const float* __restrict__ psx,
                                                  const float* __restrict__ pssx,
                                                  float* __restrict__ hm,
                                                  float* __restrict__ hiv,
                                                  float* __restrict__ xm,
                                                  float* __restrict__ xi)
{
    int f = blockIdx.x * 256 + threadIdx.x;
    if (f >= NTRIU) return;
    const float* ps  = blockIdx.y ? psx  : psh;
    const float* pss = blockIdx.y ? pssx : pssh;
    float* mo = blockIdx.y ? xm : hm;
    float* io = blockIdx.y ? xi : hiv;
    float s = 0.f, ss = 0.f;
    for (int b = 0; b < 16; ++b) {
        s  += ps [(size_t)b * NTRIU + f];
        ss += pss[(size_t)b * NTRIU + f];
    }
    float m = s * (1.0f / NGRAPH);
    mo[f] = m;
    io[f] = rsqrtf(ss * (1.0f / NGRAPH) - m * m + 1e-5f);
}

// ---------------------------------------------------------------------------
// BN statistics finalize (MLP): reduce GB partials -> mean, rsqrt(var+eps)
// ---------------------------------------------------------------------------
__global__ __launch_bounds__(256) void stats_fin(const float* __restrict__ ps,
                                                 const float* __restrict__ pss,
                                                 float* __restrict__ mean,
                                                 float* __restrict__ inv,
                                                 int F, int GB, float invR)
{
    int f = blockIdx.x * 256 + threadIdx.x;
    if (f >= F) return;
    float s = 0.f, ss = 0.f;
    for (int b = 0; b < GB; ++b) { s += ps[(size_t)b * F + f]; ss += pss[(size_t)b * F + f]; }
    float m = s * invR;
    mean[f] = m;
    inv[f]  = rsqrtf(ss * invR - m * m + 1e-5f);
}

// ---------------------------------------------------------------------------
// Fused: normalize xv & hs inline, attention dot, sigmoid, write z as
// split-bf16 (hi/lo) planes. One block per graph.
// ---------------------------------------------------------------------------
__global__ __launch_bounds__(256) void attz_fused(const float* __restrict__ xv,
                                                  const float* __restrict__ xm,
                                                  const float* __restrict__ xi,
                                                  const float* __restrict__ gx,
                                                  const float* __restrict__ bx,
                                                  const float* __restrict__ hsrc,
                                                  const float* __restrict__ hm,
                                                  const float* __restrict__ hi,
                                                  const float* __restrict__ gh,
                                                  const float* __restrict__ bh,
                                                  const float* __restrict__ Watt,
                                                  const float* __restrict__ batt,
                                                  unsigned short* __restrict__ zhi,
                                                  unsigned short* __restrict__ zlo)
{
    int g = blockIdx.x;
    __shared__ float xs[NTRIU];
    __shared__ float red[256];
    float s = 0.f;
    for (int t = threadIdx.x; t < NTRIU; t += 256) {
        float v = (xv[(size_t)g * NTRIU + t] - xm[t]) * xi[t] * gx[t] + bx[t];
        xs[t] = v;
        s += v * Watt[t];
    }
    red[threadIdx.x] = s;
    __syncthreads();
    for (int w = 128; w > 0; w >>= 1) {
        if (threadIdx.x < w) red[threadIdx.x] += red[threadIdx.x + w];
        __syncthreads();
    }
    float att = 1.0f / (1.0f + expf(-(red[0] + batt[0])));
    for (int t = threadIdx.x; t < NTRIU; t += 256) {
        float hn = (hsrc[(size_t)g * NTRIU + t] - hm[t]) * hi[t] * gh[t] + bh[t];
        float zf = att * xs[t] + (1.0f - att) * hn * 0.5f;
        unsigned short h0 = f2b(zf);
        zhi[(size_t)g * DCAT + t] = h0;
        zlo[(size_t)g * DCAT + t] = f2b(zf - b2f(h0));
        unsigned short h1 = f2b(hn);
        zhi[(size_t)g * DCAT + NTRIU + t] = h1;
        zlo[(size_t)g * DCAT + NTRIU + t] = f2b(hn - b2f(h1));
    }
}

// ---------------------------------------------------------------------------
// Split-K bf16 MFMA GEMM with hi/lo-split A:
// P[z][256][N] partial = (Ahi+Alo)[256][K-chunk] @ Bt[N][K]^T
// ---------------------------------------------------------------------------
__global__ __launch_bounds__(256) void gemm_bf_sk(const unsigned short* __restrict__ Ahi,
                                                  const unsigned short* __restrict__ Alo,
                                                  const unsigned short* __restrict__ Bt,
                                                  float* __restrict__ P,
                                                  int N, int K, int chunk)
{
    __shared__ unsigned short Ah[2][2048], Al[2][2048], Bs[2][2048];
    const int tid  = threadIdx.x;
    const int wave = tid >> 6, lane = tid & 63;
    const int row0 = blockIdx.y << 6, col0 = blockIdx.x << 6;
    const int kb = blockIdx.z * chunk;
    const int NT = chunk >> 5;
    const int sr = tid >> 2, sk = (tid & 3) << 3;
    const unsigned short* gAh = Ahi + (size_t)(row0 + sr) * K + kb + sk;
    const unsigned short* gAl = Alo + (size_t)(row0 + sr) * K + kb + sk;
    const unsigned short* gB  = Bt  + (size_t)(col0 + sr) * K + kb + sk;

    int4 rh = *(const int4*)(const void*)gAh;
    int4 rl = *(const int4*)(const void*)gAl;
    int4 rb = *(const int4*)(const void*)gB;
    *(int4*)(void*)&Ah[0][tid << 3] = rh;
    *(int4*)(void*)&Al[0][tid << 3] = rl;
    *(int4*)(void*)&Bs[0][tid << 3] = rb;
    __syncthreads();

    f32x4 acc0 = {0.f, 0.f, 0.f, 0.f};
    f32x4 acc1 = acc0, acc2 = acc0, acc3 = acc0;
    const int aoff = (wave * 16 + (lane & 15)) * 32 + ((lane >> 4) << 3);
    const int boff = (lane & 15) * 32 + ((lane >> 4) << 3);

    for (int t = 0; t < NT; ++t) {
        if (t + 1 < NT) {
            rh = *(const int4*)(const void*)(gAh + (t + 1) * 32);
            rl = *(const int4*)(const void*)(gAl + (t + 1) * 32);
            rb = *(const int4*)(const void*)(gB  + (t + 1) * 32);
        }
        const unsigned short* ah = Ah[t & 1];
        const unsigned short* al = Al[t & 1];
        const unsigned short* bs = Bs[t & 1];
        bfrag8 a  = *(const bfrag8*)(const void*)&ah[aoff];
        bfrag8 a2 = *(const bfrag8*)(const void*)&al[aoff];
        bfrag8 b0 = *(const bfrag8*)(const void*)&bs[boff];
        bfrag8 b1 = *(const bfrag8*)(const void*)&bs[boff + 16 * 32];
        bfrag8 b2 = *(const bfrag8*)(const void*)&bs[boff + 32 * 32];
        bfrag8 b3 = *(const bfrag8*)(const void*)&bs[boff + 48 * 32];
        acc0 = __builtin_amdgcn_mfma_f32_16x16x32_bf16(a,  b0, acc0, 0, 0, 0);
        acc0 = __builtin_amdgcn_mfma_f32_16x16x32_bf16(a2, b0, acc0, 0, 0, 0);
        acc1 = __builtin_amdgcn_mfma_f32_16x16x32_bf16(a,  b1, acc1, 0, 0, 0);
        acc1 = __builtin_amdgcn_mfma_f32_16x16x32_bf16(a2, b1, acc1, 0, 0, 0);
        acc2 = __builtin_amdgcn_mfma_f32_16x16x32_bf16(a,  b2, acc2, 0, 0, 0);
        acc2 = __builtin_amdgcn_mfma_f32_16x16x32_bf16(a2, b2, acc2, 0, 0, 0);
        acc3 = __builtin_amdgcn_mfma_f32_16x16x32_bf16(a,  b3, acc3, 0, 0, 0);
        acc3 = __builtin_amdgcn_mfma_f32_16x16x32_bf16(a2, b3, acc3, 0, 0, 0);
        if (t + 1 < NT) {
            *(int4*)(void*)&Ah[(t + 1) & 1][tid << 3] = rh;
            *(int4*)(void*)&Al[(t + 1) & 1][tid << 3] = rl;
            *(int4*)(void*)&Bs[(t + 1) & 1][tid << 3] = rb;
        }
        __syncthreads();
    }

    float* Pp = P + (size_t)blockIdx.z * NGRAPH * N;
    const int rbase = row0 + wave * 16 + ((lane >> 4) << 2);
    const int cbase = col0 + (lane & 15);
#pragma unroll
    for (int r = 0; r < 4; ++r) {
        int grow = rbase + r;
        Pp[(size_t)grow * N + cbase +  0] = acc0[r];
        Pp[(size_t)grow * N + cbase + 16] = acc1[r];
        Pp[(size_t)grow * N + cbase + 32] = acc2[r];
        Pp[(size_t)grow * N + cbase + 48] = acc3[r];
    }
}

// ---------------------------------------------------------------------------
// Fused split-K reduce + bias -> mf, with BN partial stats (8-row groups).
// grid (N/256, 32).
// ---------------------------------------------------------------------------
__global__ __launch_bounds__(256) void reduce_stats(const float* __restrict__ P,
                                                    const float* __restrict__ bias,
                                                    float* __restrict__ mf,
                                                    float* __restrict__ ps,
                                                    float* __restrict__ pss,
                                                    int N, int S)
{
    int f = blockIdx.x * 256 + threadIdx.x;
    int r0 = blockIdx.y * 8;
    size_t MN = (size_t)NGRAPH * N;
    float bv = bias[f];
    float s = 0.f, ss = 0.f;
    for (int r = r0; r < r0 + 8; ++r) {
        float v = 0.f;
        for (int t = 0; t < S; ++t) v += P[(size_t)t * MN + (size_t)r * N + f];
        v += bv;
        mf[(size_t)r * N + f] = v;
        s += v; ss += v * v;
    }
    ps [(size_t)blockIdx.y * N + f] = s;
    pss[(size_t)blockIdx.y * N + f] = ss;
}

// ---------------------------------------------------------------------------
// BN apply + ReLU -> split-bf16 hi/lo planes.
// ---------------------------------------------------------------------------
__global__ __launch_bounds__(256) void bn_apply_bf(const float* __restrict__ M_,
                                                   const float* __restrict__ mean,
                                                   const float* __restrict__ inv,
                                                   const float* __restrict__ gamma,
                                                   const float* __restrict__ beta,
                                                   unsigned short* __restrict__ hi,
                                                   unsigned short* __restrict__ lo,
                                                   int total, int mask)
{
    int i = blockIdx.x * 256 + threadIdx.x;
    if (i >= total) return;
    int f = i & mask;
    float v = (M_[i] - mean[f]) * inv[f] * gamma[f] + beta[f];
    v = fmaxf(v, 0.f);
    unsigned short h = f2b(v);
    hi[i] = h;
    lo[i] = f2b(v - b2f(h));
}

// ---------------------------------------------------------------------------
// Final tiny linear from hi/lo bf16: out[g][0:2] = m3[g] @ Wm4 + bm4
// ---------------------------------------------------------------------------
__global__ __launch_bounds__(256) void final_kernel(const unsigned short* __restrict__ Xhi,
                                                    const unsigned short* __restrict__ Xlo,
                                                    const float* __restrict__ W,
                                                    const float* __restrict__ b,
                                                    float* __restrict__ out)
{
    int g = blockIdx.x;
    float s0 = 0.f, s1 = 0.f;
    for (int k = threadIdx.x; k < HID2; k += 256) {
        float v = b2f(Xhi[(size_t)g * HID2 + k]) + b2f(Xlo[(size_t)g * HID2 + k]);
        s0 += v * W[k * 2 + 0];
        s1 += v * W[k * 2 + 1];
    }
    __shared__ float r0[256], r1[256];
    r0[threadIdx.x] = s0; r1[threadIdx.x] = s1;
    __syncthreads();
    for (int w = 128; w > 0; w >>= 1) {
        if (threadIdx.x < w) {
            r0[threadIdx.x] += r0[threadIdx.x + w];
            r1[threadIdx.x] += r1[threadIdx.x + w];
        }
        __syncthreads();
    }
    if (threadIdx.x == 0) {
        out[g * 2 + 0] = r0[0] + b[0];
        out[g * 2 + 1] = r1[0] + b[1];
    }
}

// ---------------------------------------------------------------------------
extern "C" void kernel_launch(void* const* d_in, const int* in_sizes, int n_in,
                              void* d_out, int out_size, void* d_ws, size_t ws_size,
                              hipStream_t stream)
{
    const float* x      = (const float*)d_in[0];
    const float* Wg0    = (const float*)d_in[1];
    const float* bg0    = (const float*)d_in[2];
    const float* WgR    = (const float*)d_in[3];
    const float* bgR    = (const float*)d_in[4];
    const float* gx     = (const float*)d_in[5];
    const float* bx     = (const float*)d_in[6];
    const float* gh     = (const float*)d_in[7];
    const float* bh     = (const float*)d_in[8];
    const float* Watt   = (const float*)d_in[9];
    const float* batt   = (const float*)d_in[10];
    const float* Wm1    = (const float*)d_in[11];
    const float* bm1    = (const float*)d_in[12];
    const float* gm1    = (const float*)d_in[13];
    const float* bem1   = (const float*)d_in[14];
    const float* Wm2    = (const float*)d_in[15];
    const float* bm2    = (const float*)d_in[16];
    const float* gm2    = (const float*)d_in[17];
    const float* bem2   = (const float*)d_in[18];
    const float* Wm3    = (const float*)d_in[19];
    const float* bm3    = (const float*)d_in[20];
    const float* gm3    = (const float*)d_in[21];
    const float* bem3   = (const float*)d_in[22];
    const float* Wm4    = (const float*)d_in[23];
    const float* bm4    = (const float*)d_in[24];
    const int*   esrc   = (const int*)d_in[25];
    const int*   edst   = (const int*)d_in[26];
    float* out = (float*)d_out;

    char* w = (char*)d_ws;
    auto alloc = [&](size_t bytes) -> char* {
        char* p = w;
        w += (bytes + 255) & ~(size_t)255;
        return p;
    };
    unsigned short* Wt0   = (unsigned short*)alloc((size_t)512 * 64 * 2);
    unsigned short* Wt123 = (unsigned short*)alloc((size_t)3 * 512 * 512 * 2);
    unsigned short* W1t   = (unsigned short*)alloc((size_t)HID1 * DCAT * 2);
    unsigned short* W2t   = (unsigned short*)alloc((size_t)HID2 * HID1 * 2);
    unsigned short* W3t   = (unsigned short*)alloc((size_t)HID2 * HID2 * 2);
    float*          hs    = (float*)alloc((size_t)NGRAPH * NTRIU * 4);
    float*          xv    = (float*)alloc((size_t)NGRAPH * NTRIU * 4);
    unsigned short* zhi   = (unsigned short*)alloc((size_t)NGRAPH * DCAT * 2);
    unsigned short* zlo   = (unsigned short*)alloc((size_t)NGRAPH * DCAT * 2);
    float*          P     = (float*)alloc((size_t)8 * NGRAPH * HID1 * 4);
    float*          mf    = (float*)alloc((size_t)NGRAPH * HID1 * 4);
    unsigned short* m1hi  = (unsigned short*)alloc((size_t)NGRAPH * HID1 * 2);
    unsigned short* m1lo  = (unsigned short*)alloc((size_t)NGRAPH * HID1 * 2);
    unsigned short* m2hi  = (unsigned short*)alloc((size_t)NGRAPH * HID2 * 2);
    unsigned short* m2lo  = (unsigned short*)alloc((size_t)NGRAPH * HID2 * 2);
    unsigned short* m3hi  = (unsigned short*)alloc((size_t)NGRAPH * HID2 * 2);
    unsigned short* m3lo  = (unsigned short*)alloc((size_t)NGRAPH * HID2 * 2);
    float*          psh   = (float*)alloc((size_t)16 * NTRIU * 4);
    float*          pssh  = (float*)alloc((size_t)16 * NTRIU * 4);
    float*          psx   = (float*)alloc((size_t)16 * NTRIU * 4);
    float*          pssx  = (float*)alloc((size_t)16 * NTRIU * 4);
    float*          ps    = (float*)alloc((size_t)32 * HID1 * 4);
    float*          pss   = (float*)alloc((size_t)32 * HID1 * 4);
    float*          xm    = (float*)alloc(NTRIU * 4);
    float*          xi    = (float*)alloc(NTRIU * 4);
    float*          hm    = (float*)alloc(NTRIU * 4);
    float*          hiv   = (float*)alloc(NTRIU * 4);
    float*          mmean = (float*)alloc(HID1 * 4);
    float*          minv  = (float*)alloc(HID1 * 4);

    hipFuncSetAttribute((const void*)gcn_all,
                        hipFuncAttributeMaxDynamicSharedMemorySize, GCN_LDS);

    convW4<<<dim3(16, 2, 1),   dim3(32, 8), 0, stream>>>(Wg0, Wt0, 64, HC, 64, 0, 0);
    convW4<<<dim3(16, 16, 3),  dim3(32, 8), 0, stream>>>(WgR, Wt123, HC, HC, 512,
                                                         (long long)HC * HC, 512LL * 512);
    convWt<<<dim3(32, 126, 1), dim3(32, 8), 0, stream>>>(Wm1, W1t, DCAT, HID1, DCAT, 0, 0);
    convWt<<<dim3(16, 32, 1),  dim3(32, 8), 0, stream>>>(Wm2, W2t, HID1, HID2, HID1, 0, 0);
    convWt<<<dim3(16, 16, 1),  dim3(32, 8), 0, stream>>>(Wm3, W3t, HID2, HID2, HID2, 0, 0);

    // Whole GCN (adjacency build + 4 layers + pool) in one kernel, 16 waves
    gcn_all<<<NGRAPH, 1024, GCN_LDS, stream>>>(x, esrc, edst, Wt0, Wt123, bg0, bgR, hs);

    // BN stats for h and xv (one dual-job kernel), finalize, fused att+z
    pre_stats<<<dim3(8, 16, 2), 256, 0, stream>>>(hs, x, xv, psh, pssh, psx, pssx);
    stats_fin2<<<dim3(8, 2), 256, 0, stream>>>(psh, pssh, psx, pssx, hm, hiv, xm, xi);
    attz_fused<<<NGRAPH, 256, 0, stream>>>(xv, xm, xi, gx, bx, hs, hm, hiv, gh, bh,
                                           Watt, batt, zhi, zlo);

    // MLP layer 1: [256,4032] @ [4032,1024]
    gemm_bf_sk<<<dim3(16, 4, 7), 256, 0, stream>>>(zhi, zlo, W1t, P, HID1, DCAT, 576);
    reduce_stats<<<dim3(4, 32), 256, 0, stream>>>(P, bm1, mf, ps, pss, HID1, 7);
    stats_fin<<<4, 256, 0, stream>>>(ps, pss, mmean, minv, HID1, 32, 1.0f / NGRAPH);
    bn_apply_bf<<<1024, 256, 0, stream>>>(mf, mmean, minv, gm1, bem1, m1hi, m1lo,
                                          NGRAPH * HID1, HID1 - 1);

    // MLP layer 2: [256,1024] @ [1024,512]
    gemm_bf_sk<<<dim3(8, 4, 8), 256, 0, stream>>>(m1hi, m1lo, W2t, P, HID2, HID1, 128);
    reduce_stats<<<dim3(2, 32), 256, 0, stream>>>(P, bm2, mf, ps, pss, HID2, 8);
    stats_fin<<<2, 256, 0, stream>>>(ps, pss, mmean, minv, HID2, 32, 1.0f / NGRAPH);
    bn_apply_bf<<<512, 256, 0, stream>>>(mf, mmean, minv, gm2, bem2, m2hi, m2lo,
                                         NGRAPH * HID2, HID2 - 1);

    // MLP layer 3: [256,512] @ [512,512]
    gemm_bf_sk<<<dim3(8, 4, 8), 256, 0, stream>>>(m2hi, m2lo, W3t, P, HID2, HID2, 64);
    reduce_stats<<<dim3(2, 32), 256, 0, stream>>>(P, bm3, mf, ps, pss, HID2, 8);
    stats_fin<<<2, 256, 0, stream>>>(ps, pss, mmean, minv, HID2, 32, 1.0f / NGRAPH);
    bn_apply_bf<<<512, 256, 0, stream>>>(mf, mmean, minv, gm3, bem3, m3hi, m3lo,
                                         NGRAPH * HID2, HID2 - 1);

    final_kernel<<<NGRAPH, 256, 0, stream>>>(m3hi, m3lo, Wm4, bm4, out);
}

// Round 10
// 162.037 us; speedup vs baseline: 1.2543x; 1.1497x over previous
//
#include <hip/hip_runtime.h>
#include <math.h>

#define NGRAPH 256
#define NPG 64
#define NFEAT 64
#define HC 504
#define NLAY 4
#define EPER 1024
#define NTRIU 2016
#define DCAT 4032
#define HID1 1024
#define HID2 512

// cur 65536 + xwt 73728 + ahl(2 planes, pitch 72) 18432 = 157696 B <= 160KiB
#define GCN_LDS (65536 + 73728 + 18432)
#define AHL_LO 4608   // 64*72 elements: offset of lo plane

typedef __attribute__((ext_vector_type(8))) short bfrag8;   // 8 bf16 in 4 VGPRs
typedef __attribute__((ext_vector_type(4))) float f32x4;

struct __align__(8) us4 { unsigned short a, b, c, d; };

__device__ __forceinline__ unsigned short f2b(float f) {
    union { float f; unsigned u; } v; v.f = f;
    unsigned r = (v.u + 0x7fffu + ((v.u >> 16) & 1u)) >> 16;   // RNE
    return (unsigned short)r;
}
__device__ __forceinline__ float b2f(unsigned short h) {
    union { unsigned u; float f; } v; v.u = ((unsigned)h) << 16;
    return v.f;
}

// ---------------------------------------------------------------------------
// Batched GCN weight convert to MFMA-fragment-major layout:
// z=0 -> Wg0 (K=64, KL=64), z=1..3 -> WgR[z-1] (K=HC, KL=512). N=HC always.
// elem (n,k) -> ((n>>4)*(KL/32) + (k>>5))*512 + ((k>>3)&3)*128 + (n&15)*8 + (k&7)
// ---------------------------------------------------------------------------
__global__ void conv_gcn(const float* __restrict__ Wg0, const float* __restrict__ WgR,
                         unsigned short* __restrict__ Wt0, unsigned short* __restrict__ Wt123)
{
    const int z = blockIdx.z;
    const float* W;
    unsigned short* W4;
    int K, KL;
    if (z == 0) {
        if (blockIdx.y >= 2) return;
        W = Wg0; W4 = Wt0; K = 64; KL = 64;
    } else {
        W = WgR + (size_t)(z - 1) * HC * HC;
        W4 = Wt123 + (size_t)(z - 1) * 262144;
        K = HC; KL = 512;
    }
    __shared__ float T[32][33];
    int k0 = blockIdx.y * 32, n0 = blockIdx.x * 32;
    int tx = threadIdx.x, ty = threadIdx.y;
#pragma unroll
    for (int j = 0; j < 32; j += 8) {
        int k = k0 + ty + j, n = n0 + tx;
        T[ty + j][tx] = (k < K && n < HC) ? W[(size_t)k * HC + n] : 0.f;
    }
    __syncthreads();
#pragma unroll
    for (int j = 0; j < 32; j += 8) {
        int n = n0 + ty + j, k = k0 + tx;
        int idx = ((n >> 4) * (KL >> 5) + (k >> 5)) * 512
                + (((k >> 3) & 3) << 7) + ((n & 15) << 3) + (k & 7);
        W4[idx] = f2b(T[tx][ty + j]);
    }
}

// ---------------------------------------------------------------------------
// Batched MLP weight transpose+convert: Wt[n][k] = bf16(W[k][n]), pitch K.
// z=0: Wm1 (4032->1024), z=1: Wm2 (1024->512), z=2: Wm3 (512->512).
// grid (32, 126, 3); out-of-range tiles early-exit.
// ---------------------------------------------------------------------------
__global__ void conv_mlp(const float* __restrict__ Wm1, const float* __restrict__ Wm2,
                         const float* __restrict__ Wm3,
                         unsigned short* __restrict__ W1t, unsigned short* __restrict__ W2t,
                         unsigned short* __restrict__ W3t)
{
    const int z = blockIdx.z;
    const float* W;
    unsigned short* Wt;
    int K, N;
    if (z == 0)      { W = Wm1; Wt = W1t; K = DCAT; N = HID1; }
    else if (z == 1) { W = Wm2; Wt = W2t; K = HID1; N = HID2; }
    else             { W = Wm3; Wt = W3t; K = HID2; N = HID2; }
    int k0 = blockIdx.y * 32, n0 = blockIdx.x * 32;
    if (k0 >= K || n0 >= N) return;
    __shared__ float T[32][33];
    int tx = threadIdx.x, ty = threadIdx.y;
#pragma unroll
    for (int j = 0; j < 32; j += 8) {
        int k = k0 + ty + j, n = n0 + tx;
        T[ty + j][tx] = (k < K && n < N) ? W[(size_t)k * N + n] : 0.f;
    }
    __syncthreads();
#pragma unroll
    for (int j = 0; j < 32; j += 8) {
        int n = n0 + ty + j, k = k0 + tx;
        Wt[(size_t)n * K + k] = f2b(T[tx][ty + j]);
    }
}

// ---------------------------------------------------------------------------
// One GCN layer, one graph, 16 waves: wave wv owns 32 cols [wv*32, wv*32+32).
// ahl pitch = 72 elements (144B rows) -> adjacency ds_read_b128 conflict-free.
// ---------------------------------------------------------------------------
template<int KL>
__device__ __forceinline__ void gcn_layer(const unsigned short* __restrict__ W4,
                                          const float* __restrict__ bias,
                                          unsigned short* cur, unsigned short* xwt,
                                          const unsigned short* ahl,
                                          float* __restrict__ hsg,
                                          int wv, int lm, int lh)
{
    constexpr int KTS = KL >> 5;
    const int colw = wv << 5;             // 32 cols per wave
    const int kswz = (lm & 7) << 3;
    const int lane8 = ((lh << 4) + lm) << 3;   // lane * 8

    f32x4 acc[4][2];
#pragma unroll
    for (int m0 = 0; m0 < 4; ++m0)
#pragma unroll
        for (int cc = 0; cc < 2; ++cc) acc[m0][cc] = (f32x4){0.f, 0.f, 0.f, 0.f};

    // ---- phase 1: feature GEMM with depth-2 weight prefetch ----
    bfrag8 bq[2][2];
#pragma unroll
    for (int cc = 0; cc < 2; ++cc)
        bq[0][cc] = *(const bfrag8*)(const void*)&W4[(size_t)((wv * 2 + cc) * KTS + 0) * 512 + lane8];
    if (KTS > 1) {
#pragma unroll
        for (int cc = 0; cc < 2; ++cc)
            bq[1][cc] = *(const bfrag8*)(const void*)&W4[(size_t)((wv * 2 + cc) * KTS + 1) * 512 + lane8];
    }
#pragma unroll
    for (int kt = 0; kt < KTS; ++kt) {
        bfrag8 a[4];
#pragma unroll
        for (int m0 = 0; m0 < 4; ++m0)
            a[m0] = *(const bfrag8*)(const void*)&cur[(m0 * 16 + lm) * 512 + ((kt * 32 + (lh << 3)) ^ kswz)];
        bfrag8 bc[2];
        bc[0] = bq[kt & 1][0]; bc[1] = bq[kt & 1][1];
        if (kt + 2 < KTS) {
#pragma unroll
            for (int cc = 0; cc < 2; ++cc)
                bq[kt & 1][cc] = *(const bfrag8*)(const void*)&W4[(size_t)((wv * 2 + cc) * KTS + kt + 2) * 512 + lane8];
        }
#pragma unroll
        for (int cc = 0; cc < 2; ++cc)
#pragma unroll
            for (int m0 = 0; m0 < 4; ++m0)
                acc[m0][cc] = __builtin_amdgcn_mfma_f32_16x16x32_bf16(a[m0], bc[cc], acc[m0][cc], 0, 0, 0);
    }
    __syncthreads();   // all waves' cur reads complete before epilogue rewrites cur

    // ---- write XW^T to wave-private xwt cols (us4; no barrier needed) ----
#pragma unroll
    for (int cc = 0; cc < 2; ++cc) {
        const int c = colw + cc * 16 + lm;
#pragma unroll
        for (int m0 = 0; m0 < 4; ++m0) {
            us4 p;
            p.a = f2b(acc[m0][cc][0]); p.b = f2b(acc[m0][cc][1]);
            p.c = f2b(acc[m0][cc][2]); p.d = f2b(acc[m0][cc][3]);
            *(us4*)(void*)&xwt[c * 72 + m0 * 16 + (lh << 2)] = p;
        }
    }

    // ---- phase 2 (swapped): acc2[cc][n0] = Y^T tile ----
    f32x4 acc2[2][4];
#pragma unroll
    for (int cc = 0; cc < 2; ++cc)
#pragma unroll
        for (int n0 = 0; n0 < 4; ++n0) acc2[cc][n0] = (f32x4){0.f, 0.f, 0.f, 0.f};
#pragma unroll
    for (int n0 = 0; n0 < 4; ++n0) {
        const int o = (n0 * 16 + lm) * 72 + (lh << 3);   // pitch 72: conflict-free
        bfrag8 bh0 = *(const bfrag8*)(const void*)&ahl[o];
        bfrag8 bh1 = *(const bfrag8*)(const void*)&ahl[o + 32];
        bfrag8 bl0 = *(const bfrag8*)(const void*)&ahl[AHL_LO + o];
        bfrag8 bl1 = *(const bfrag8*)(const void*)&ahl[AHL_LO + o + 32];
#pragma unroll
        for (int cc = 0; cc < 2; ++cc) {
            const int c = colw + cc * 16 + lm;
            bfrag8 a0 = *(const bfrag8*)(const void*)&xwt[c * 72 + (lh << 3)];
            bfrag8 a1 = *(const bfrag8*)(const void*)&xwt[c * 72 + 32 + (lh << 3)];
            acc2[cc][n0] = __builtin_amdgcn_mfma_f32_16x16x32_bf16(a0, bh0, acc2[cc][n0], 0, 0, 0);
            acc2[cc][n0] = __builtin_amdgcn_mfma_f32_16x16x32_bf16(a0, bl0, acc2[cc][n0], 0, 0, 0);
            acc2[cc][n0] = __builtin_amdgcn_mfma_f32_16x16x32_bf16(a1, bh1, acc2[cc][n0], 0, 0, 0);
            acc2[cc][n0] = __builtin_amdgcn_mfma_f32_16x16x32_bf16(a1, bl1, acc2[cc][n0], 0, 0, 0);
        }
    }

    // ---- bias + us4 writeback to cur + pool (shfl over lm) ----
#pragma unroll
    for (int cc = 0; cc < 2; ++cc) {
        const int cb = colw + cc * 16 + (lh << 2);   // 4 consecutive cols
        float bv[4];
#pragma unroll
        for (int r = 0; r < 4; ++r) {
            int c = cb + r;
            bv[r] = (c < HC) ? bias[c] : 0.f;
        }
        float t0 = 0.f, t1 = 0.f, t2 = 0.f, t3 = 0.f;
#pragma unroll
        for (int n0 = 0; n0 < 4; ++n0) {
            const int d = n0 * 16 + lm;              // node
            float v0 = acc2[cc][n0][0] + bv[0];
            float v1 = acc2[cc][n0][1] + bv[1];
            float v2 = acc2[cc][n0][2] + bv[2];
            float v3 = acc2[cc][n0][3] + bv[3];
            t0 += v0; t1 += v1; t2 += v2; t3 += v3;
            us4 p;
            p.a = f2b(v0); p.b = f2b(v1); p.c = f2b(v2); p.d = f2b(v3);
            *(us4*)(void*)&cur[d * 512 + (cb ^ ((d & 7) << 3))] = p;
        }
#pragma unroll
        for (int m = 1; m < 16; m <<= 1) {
            t0 += __shfl_xor(t0, m, 64);
            t1 += __shfl_xor(t1, m, 64);
            t2 += __shfl_xor(t2, m, 64);
            t3 += __shfl_xor(t3, m, 64);
        }
        if (lm == 0 && cb < HC)
            *(float4*)&hsg[cb] = make_float4(t0 * (1.0f / 64.0f), t1 * (1.0f / 64.0f),
                                             t2 * (1.0f / 64.0f), t3 * (1.0f / 64.0f));
    }
    __syncthreads();   // cur complete before next layer's feature reads
}

// ---------------------------------------------------------------------------
// Whole-GCN mega-kernel: one block = one graph, 16 waves, all 4 layers in LDS.
// ---------------------------------------------------------------------------
__global__ __launch_bounds__(1024, 4) void gcn_all(const float* __restrict__ x,
                                                   const int* __restrict__ esrc,
                                                   const int* __restrict__ edst,
                                                   const unsigned short* __restrict__ Wt0,
                                                   const unsigned short* __restrict__ Wt123,
                                                   const float* __restrict__ bg0,
                                                   const float* __restrict__ bgR,
                                                   float* __restrict__ hs)
{
    extern __shared__ char lds[];
    unsigned short* cur = (unsigned short*)lds;                    // 65536 B
    unsigned short* xwt = (unsigned short*)(lds + 65536);          // 73728 B
    unsigned short* ahl = (unsigned short*)(lds + 65536 + 73728);  // 18432 B (pitch 72)
    float* Af   = (float*)(lds + 65536);                           // scratch in xwt
    int*   cnt  = (int*)(lds + 65536 + 16384);
    float* dinv = (float*)(lds + 65536 + 16384 + 256);

    const int g = blockIdx.x, tid = threadIdx.x;
    const int wv = tid >> 6, lane = tid & 63;
    const int lm = lane & 15, lh = lane >> 4;

    // ---- build normalized adjacency in LDS ----
    for (int i = tid; i < 4096; i += 1024) Af[i] = 0.f;
    if (tid < 64) cnt[tid] = 0;
    __syncthreads();
    atomicAdd(&cnt[edst[(size_t)g * EPER + tid] & 63], 1);
    __syncthreads();
    if (tid < 64) dinv[tid] = rsqrtf((float)cnt[tid] + 1.0f);
    __syncthreads();
    {
        int s = esrc[(size_t)g * EPER + tid] & 63;
        int d = edst[(size_t)g * EPER + tid] & 63;
        atomicAdd(&Af[d * 64 + s], dinv[s] * dinv[d]);
    }
    __syncthreads();
    if (tid < 64) Af[tid * 64 + tid] += dinv[tid] * dinv[tid];
    __syncthreads();
    for (int i = tid; i < 4096; i += 1024) {
        float v = Af[i];
        unsigned short h = f2b(v);
        int d = i >> 6, s = i & 63;
        ahl[d * 72 + s] = h;
        ahl[AHL_LO + d * 72 + s] = f2b(v - b2f(h));
    }
    // ---- load x -> cur (bf16, swizzled); layer0 uses k<64 only ----
    {
        float4 v = ((const float4*)(x + (size_t)g * 4096))[tid];
        int row = (tid * 4) >> 6, col = (tid * 4) & 63;
        unsigned short* p = &cur[row * 512 + (col ^ ((row & 7) << 3))];
        p[0] = f2b(v.x); p[1] = f2b(v.y); p[2] = f2b(v.z); p[3] = f2b(v.w);
    }
    __syncthreads();

    float* hsg = hs + (size_t)g * (HC * NLAY);
    gcn_layer<64>(Wt0, bg0, cur, xwt, ahl, hsg, wv, lm, lh);
    for (int l = 1; l < NLAY; ++l)
        gcn_layer<512>(Wt123 + (size_t)(l - 1) * 262144, bgR + (l - 1) * HC,
                       cur, xwt, ahl, hsg + l * HC, wv, lm, lh);
}

// ---------------------------------------------------------------------------
// Dual-job pre-BN kernel: z=0 -> hs partial stats; z=1 -> xv gather + stats.
// grid (8, 16, 2).
// ---------------------------------------------------------------------------
__global__ __launch_bounds__(256) void pre_stats(const float* __restrict__ hs,
                                                 const float* __restrict__ x,
                                                 float* __restrict__ xv,
                                                 float* __restrict__ psh,
                                                 float* __restrict__ pssh,
                                                 float* __restrict__ psx,
                                                 float* __restrict__ pssx)
{
    int t = blockIdx.x * 256 + threadIdx.x;
    if (t >= NTRIU) return;
    int g0 = blockIdx.y * 16;
    if (blockIdx.z == 0) {
        float s = 0.f, ss = 0.f;
        for (int g = g0; g < g0 + 16; ++g) {
            float v = hs[(size_t)g * NTRIU + t];
            s += v; ss += v * v;
        }
        psh [(size_t)blockIdx.y * NTRIU + t] = s;
        pssh[(size_t)blockIdx.y * NTRIU + t] = ss;
    } else {
        int i = (int)(63.5f - sqrtf(63.5f * 63.5f - 2.0f * (float)t));
        while (63 * (i + 1) - (i + 1) * i / 2 <= t) ++i;
        while (63 * i - i * (i - 1) / 2 > t) --i;
        int j = t - (63 * i - i * (i - 1) / 2) + i + 1;
        int o = i * 64 + j;
        float s = 0.f, ss = 0.f;
        for (int g = g0; g < g0 + 16; ++g) {
            float v = x[(size_t)g * 4096 + o];
            xv[(size_t)g * NTRIU + t] = v;
            s += v; ss += v * v;
        }
        psx [(size_t)blockIdx.y * NTRIU + t] = s;
        pssx[(size_t)blockIdx.y * NTRIU + t] = ss;
    }
}

// ---------------------------------------------------------------------------
// Dual stats finalize: y=0 -> (psh -> hm,hiv), y=1 -> (psx -> xm,xi). grid (8,2).
// ---------------------------------------------------------------------------
__global__ __launch_bounds__(256) void stats_fin2(const float* __restrict__ psh,
                                                  const float* __restrict__ pssh,
                                                  const float* __restrict__ psx,
                                                  const float* __restrict__ pssx,
                                                  float* __restrict__ hm,
                                                  float* __restrict__ hiv,
                                                  float* __restrict__ xm,
                                                  float* __restrict__ xi)
{
    int f = blockIdx.x * 256 + threadIdx.x;
    if (f >= NTRIU) return;
    const float* ps  = blockIdx.y ? psx  : psh;
    const float* pss = blockIdx.y ? pssx : pssh;
    float* mo = blockIdx.y ? xm : hm;
    float* io = blockIdx.y ? xi : hiv;
    float s = 0.f, ss = 0.f;
    for (int b = 0; b < 16; ++b) {
        s  += ps [(size_t)b * NTRIU + f];
        ss += pss[(size_t)b * NTRIU + f];
    }
    float m = s * (1.0f / NGRAPH);
    mo[f] = m;
    io[f] = rsqrtf(ss * (1.0f / NGRAPH) - m * m + 1e-5f);
}

// ---------------------------------------------------------------------------
// Fused: normalize xv & hs inline, attention dot, sigmoid, write z as
// split-bf16 (hi/lo) planes. One block per graph.
// ---------------------------------------------------------------------------
__global__ __launch_bounds__(256) void attz_fused(const float* __restrict__ xv,
                                                  const float* __restrict__ xm,
                                                  const float* __restrict__ xi,
                                                  const float* __restrict__ gx,
                                                  const float* __restrict__ bx,
                                                  const float* __restrict__ hsrc,
                                                  const float* __restrict__ hm,
                                                  const float* __restrict__ hi,
                                                  const float* __restrict__ gh,
                                                  const float* __restrict__ bh,
                                                  const float* __restrict__ Watt,
                                                  const float* __restrict__ batt,
                                                  unsigned short* __restrict__ zhi,
                                                  unsigned short* __restrict__ zlo)
{
    int g = blockIdx.x;
    __shared__ float xs[NTRIU];
    __shared__ float red[256];
    float s = 0.f;
    for (int t = threadIdx.x; t < NTRIU; t += 256) {
        float v = (xv[(size_t)g * NTRIU + t] - xm[t]) * xi[t] * gx[t] + bx[t];
        xs[t] = v;
        s += v * Watt[t];
    }
    red[threadIdx.x] = s;
    __syncthreads();
    for (int w = 128; w > 0; w >>= 1) {
        if (threadIdx.x < w) red[threadIdx.x] += red[threadIdx.x + w];
        __syncthreads();
    }
    float att = 1.0f / (1.0f + expf(-(red[0] + batt[0])));
    for (int t = threadIdx.x; t < NTRIU; t += 256) {
        float hn = (hsrc[(size_t)g * NTRIU + t] - hm[t]) * hi[t] * gh[t] + bh[t];
        float zf = att * xs[t] + (1.0f - att) * hn * 0.5f;
        unsigned short h0 = f2b(zf);
        zhi[(size_t)g * DCAT + t] = h0;
        zlo[(size_t)g * DCAT + t] = f2b(zf - b2f(h0));
        unsigned short h1 = f2b(hn);
        zhi[(size_t)g * DCAT + NTRIU + t] = h1;
        zlo[(size_t)g * DCAT + NTRIU + t] = f2b(hn - b2f(h1));
    }
}

// ---------------------------------------------------------------------------
// Split-K bf16 MFMA GEMM with hi/lo-split A:
// P[z][256][N] partial = (Ahi+Alo)[256][K-chunk] @ Bt[N][K]^T
// ---------------------------------------------------------------------------
__global__ __launch_bounds__(256) void gemm_bf_sk(const unsigned short* __restrict__ Ahi,
                                                  const unsigned short* __restrict__ Alo,
                                                  const unsigned short* __restrict__ Bt,
                                                  float* __restrict__ P,
                                                  int N, int K, int chunk)
{
    __shared__ unsigned short Ah[2][2048], Al[2][2048], Bs[2][2048];
    const int tid  = threadIdx.x;
    const int wave = tid >> 6, lane = tid & 63;
    const int row0 = blockIdx.y << 6, col0 = blockIdx.x << 6;
    const int kb = blockIdx.z * chunk;
    const int NT = chunk >> 5;
    const int sr = tid >> 2, sk = (tid & 3) << 3;
    const unsigned short* gAh = Ahi + (size_t)(row0 + sr) * K + kb + sk;
    const unsigned short* gAl = Alo + (size_t)(row0 + sr) * K + kb + sk;
    const unsigned short* gB  = Bt  + (size_t)(col0 + sr) * K + kb + sk;

    int4 rh = *(const int4*)(const void*)gAh;
    int4 rl = *(const int4*)(const void*)gAl;
    int4 rb = *(const int4*)(const void*)gB;
    *(int4*)(void*)&Ah[0][tid << 3] = rh;
    *(int4*)(void*)&Al[0][tid << 3] = rl;
    *(int4*)(void*)&Bs[0][tid << 3] = rb;
    __syncthreads();

    f32x4 acc0 = {0.f, 0.f, 0.f, 0.f};
    f32x4 acc1 = acc0, acc2 = acc0, acc3 = acc0;
    const int aoff = (wave * 16 + (lane & 15)) * 32 + ((lane >> 4) << 3);
    const int boff = (lane & 15) * 32 + ((lane >> 4) << 3);

    for (int t = 0; t < NT; ++t) {
        if (t + 1 < NT) {
            rh = *(const int4*)(const void*)(gAh + (t + 1) * 32);
            rl = *(const int4*)(const void*)(gAl + (t + 1) * 32);
            rb = *(const int4*)(const void*)(gB  + (t + 1) * 32);
        }
        const unsigned short* ah = Ah[t & 1];
        const unsigned short* al = Al[t & 1];
        const unsigned short* bs = Bs[t & 1];
        bfrag8 a  = *(const bfrag8*)(const void*)&ah[aoff];
        bfrag8 a2 = *(const bfrag8*)(const void*)&al[aoff];
        bfrag8 b0 = *(const bfrag8*)(const void*)&bs[boff];
        bfrag8 b1 = *(const bfrag8*)(const void*)&bs[boff + 16 * 32];
        bfrag8 b2 = *(const bfrag8*)(const void*)&bs[boff + 32 * 32];
        bfrag8 b3 = *(const bfrag8*)(const void*)&bs[boff + 48 * 32];
        acc0 = __builtin_amdgcn_mfma_f32_16x16x32_bf16(a,  b0, acc0, 0, 0, 0);
        acc0 = __builtin_amdgcn_mfma_f32_16x16x32_bf16(a2, b0, acc0, 0, 0, 0);
        acc1 = __builtin_amdgcn_mfma_f32_16x16x32_bf16(a,  b1, acc1, 0, 0, 0);
        acc1 = __builtin_amdgcn_mfma_f32_16x16x32_bf16(a2, b1, acc1, 0, 0, 0);
        acc2 = __builtin_amdgcn_mfma_f32_16x16x32_bf16(a,  b2, acc2, 0, 0, 0);
        acc2 = __builtin_amdgcn_mfma_f32_16x16x32_bf16(a2, b2, acc2, 0, 0, 0);
        acc3 = __builtin_amdgcn_mfma_f32_16x16x32_bf16(a,  b3, acc3, 0, 0, 0);
        acc3 = __builtin_amdgcn_mfma_f32_16x16x32_bf16(a2, b3, acc3, 0, 0, 0);
        if (t + 1 < NT) {
            *(int4*)(void*)&Ah[(t + 1) & 1][tid << 3] = rh;
            *(int4*)(void*)&Al[(t + 1) & 1][tid << 3] = rl;
            *(int4*)(void*)&Bs[(t + 1) & 1][tid << 3] = rb;
        }
        __syncthreads();
    }

    float* Pp = P + (size_t)blockIdx.z * NGRAPH * N;
    const int rbase = row0 + wave * 16 + ((lane >> 4) << 2);
    const int cbase = col0 + (lane & 15);
#pragma unroll
    for (int r = 0; r < 4; ++r) {
        int grow = rbase + r;
        Pp[(size_t)grow * N + cbase +  0] = acc0[r];
        Pp[(size_t)grow * N + cbase + 16] = acc1[r];
        Pp[(size_t)grow * N + cbase + 32] = acc2[r];
        Pp[(size_t)grow * N + cbase + 48] = acc3[r];
    }
}

// ---------------------------------------------------------------------------
// Fused split-K reduce + bias -> mf, with BN partial stats (8-row groups).
// grid (N/256, 32).
// ---------------------------------------------------------------------------
__global__ __launch_bounds__(256) void reduce_stats(const float* __restrict__ P,
                                                    const float* __restrict__ bias,
                                                    float* __restrict__ mf,
                                                    float* __restrict__ ps,
                                                    float* __restrict__ pss,
                                                    int N, int S)
{
    int f = blockIdx.x * 256 + threadIdx.x;
    int r0 = blockIdx.y * 8;
    size_t MN = (size_t)NGRAPH * N;
    float bv = bias[f];
    float s = 0.f, ss = 0.f;
    for (int r = r0; r < r0 + 8; ++r) {
        float v = 0.f;
        for (int t = 0; t < S; ++t) v += P[(size_t)t * MN + (size_t)r * N + f];
        v += bv;
        mf[(size_t)r * N + f] = v;
        s += v; ss += v * v;
    }
    ps [(size_t)blockIdx.y * N + f] = s;
    pss[(size_t)blockIdx.y * N + f] = ss;
}

// ---------------------------------------------------------------------------
// Fused BN finalize + apply + ReLU -> split-bf16 hi/lo planes.
// Each block redundantly reduces the 32 stat partials for its 256 features
// (32KB read, cheap), then applies to 8 rows. grid (N/256, 32).
// ---------------------------------------------------------------------------
__global__ __launch_bounds__(256) void fin_apply(const float* __restrict__ ps,
                                                 const float* __restrict__ pss,
                                                 const float* __restrict__ mf,
                                                 const float* __restrict__ gamma,
                                                 const float* __restrict__ beta,
                                                 unsigned short* __restrict__ hi,
                                                 unsigned short* __restrict__ lo,
                                                 int N)
{
    int f = blockIdx.x * 256 + threadIdx.x;
    float s = 0.f, ss = 0.f;
#pragma unroll 8
    for (int b = 0; b < 32; ++b) {
        s  += ps [(size_t)b * N + f];
        ss += pss[(size_t)b * N + f];
    }
    float m  = s * (1.0f / NGRAPH);
    float iv = rsqrtf(ss * (1.0f / NGRAPH) - m * m + 1e-5f) * gamma[f];
    float bt = beta[f];
    int r0 = blockIdx.y * 8;
    for (int r = r0; r < r0 + 8; ++r) {
        float v = (mf[(size_t)r * N + f] - m) * iv + bt;
        v = fmaxf(v, 0.f);
        unsigned short h = f2b(v);
        hi[(size_t)r * N + f] = h;
        lo[(size_t)r * N + f] = f2b(v - b2f(h));
    }
}

// ---------------------------------------------------------------------------
// Final tiny linear from hi/lo bf16: out[g][0:2] = m3[g] @ Wm4 + bm4
// ---------------------------------------------------------------------------
__global__ __launch_bounds__(256) void final_kernel(const unsigned short* __restrict__ Xhi,
                                                    const unsigned short* __restrict__ Xlo,
                                                    const float* __restrict__ W,
                                                    const float* __restrict__ b,
                                                    float* __restrict__ out)
{
    int g = blockIdx.x;
    float s0 = 0.f, s1 = 0.f;
    for (int k = threadIdx.x; k < HID2; k += 256) {
        float v = b2f(Xhi[(size_t)g * HID2 + k]) + b2f(Xlo[(size_t)g * HID2 + k]);
        s0 += v * W[k * 2 + 0];
        s1 += v * W[k * 2 + 1];
    }
    __shared__ float r0[256], r1[256];
    r0[threadIdx.x] = s0; r1[threadIdx.x] = s1;
    __syncthreads();
    for (int w = 128; w > 0; w >>= 1) {
        if (threadIdx.x < w) {
            r0[threadIdx.x] += r0[threadIdx.x + w];
            r1[threadIdx.x] += r1[threadIdx.x + w];
        }
        __syncthreads();
    }
    if (threadIdx.x == 0) {
        out[g * 2 + 0] = r0[0] + b[0];
        out[g * 2 + 1] = r1[0] + b[1];
    }
}

// ---------------------------------------------------------------------------
extern "C" void kernel_launch(void* const* d_in, const int* in_sizes, int n_in,
                              void* d_out, int out_size, void* d_ws, size_t ws_size,
                              hipStream_t stream)
{
    const float* x      = (const float*)d_in[0];
    const float* Wg0    = (const float*)d_in[1];
    const float* bg0    = (const float*)d_in[2];
    const float* WgR    = (const float*)d_in[3];
    const float* bgR    = (const float*)d_in[4];
    const float* gx     = (const float*)d_in[5];
    const float* bx     = (const float*)d_in[6];
    const float* gh     = (const float*)d_in[7];
    const float* bh     = (const float*)d_in[8];
    const float* Watt   = (const float*)d_in[9];
    const float* batt   = (const float*)d_in[10];
    const float* Wm1    = (const float*)d_in[11];
    const float* bm1    = (const float*)d_in[12];
    const float* gm1    = (const float*)d_in[13];
    const float* bem1   = (const float*)d_in[14];
    const float* Wm2    = (const float*)d_in[15];
    const float* bm2    = (const float*)d_in[16];
    const float* gm2    = (const float*)d_in[17];
    const float* bem2   = (const float*)d_in[18];
    const float* Wm3    = (const float*)d_in[19];
    const float* bm3    = (const float*)d_in[20];
    const float* gm3    = (const float*)d_in[21];
    const float* bem3   = (const float*)d_in[22];
    const float* Wm4    = (const float*)d_in[23];
    const float* bm4    = (const float*)d_in[24];
    const int*   esrc   = (const int*)d_in[25];
    const int*   edst   = (const int*)d_in[26];
    float* out = (float*)d_out;

    char* w = (char*)d_ws;
    auto alloc = [&](size_t bytes) -> char* {
        char* p = w;
        w += (bytes + 255) & ~(size_t)255;
        return p;
    };
    unsigned short* Wt0   = (unsigned short*)alloc((size_t)512 * 64 * 2);
    unsigned short* Wt123 = (unsigned short*)alloc((size_t)3 * 512 * 512 * 2);
    unsigned short* W1t   = (unsigned short*)alloc((size_t)HID1 * DCAT * 2);
    unsigned short* W2t   = (unsigned short*)alloc((size_t)HID2 * HID1 * 2);
    unsigned short* W3t   = (unsigned short*)alloc((size_t)HID2 * HID2 * 2);
    float*          hs    = (float*)alloc((size_t)NGRAPH * NTRIU * 4);
    float*          xv    = (float*)alloc((size_t)NGRAPH * NTRIU * 4);
    unsigned short* zhi   = (unsigned short*)alloc((size_t)NGRAPH * DCAT * 2);
    unsigned short* zlo   = (unsigned short*)alloc((size_t)NGRAPH * DCAT * 2);
    float*          P     = (float*)alloc((size_t)8 * NGRAPH * HID1 * 4);
    float*          mf    = (float*)alloc((size_t)NGRAPH * HID1 * 4);
    unsigned short* m1hi  = (unsigned short*)alloc((size_t)NGRAPH * HID1 * 2);
    unsigned short* m1lo  = (unsigned short*)alloc((size_t)NGRAPH * HID1 * 2);
    unsigned short* m2hi  = (unsigned short*)alloc((size_t)NGRAPH * HID2 * 2);
    unsigned short* m2lo  = (unsigned short*)alloc((size_t)NGRAPH * HID2 * 2);
    unsigned short* m3hi  = (unsigned short*)alloc((size_t)NGRAPH * HID2 * 2);
    unsigned short* m3lo  = (unsigned short*)alloc((size_t)NGRAPH * HID2 * 2);
    float*          psh   = (float*)alloc((size_t)16 * NTRIU * 4);
    float*          pssh  = (float*)alloc((size_t)16 * NTRIU * 4);
    float*          psx   = (float*)alloc((size_t)16 * NTRIU * 4);
    float*          pssx  = (float*)alloc((size_t)16 * NTRIU * 4);
    float*          ps    = (float*)alloc((size_t)32 * HID1 * 4);
    float*          pss   = (float*)alloc((size_t)32 * HID1 * 4);
    float*          xm    = (float*)alloc(NTRIU * 4);
    float*          xi    = (float*)alloc(NTRIU * 4);
    float*          hm    = (float*)alloc(NTRIU * 4);
    float*          hiv   = (float*)alloc(NTRIU * 4);

    hipFuncSetAttribute((const void*)gcn_all,
                        hipFuncAttributeMaxDynamicSharedMemorySize, GCN_LDS);

    // Weight conversions: 2 batched launches (GCN fragment-major, MLP transposed)
    conv_gcn<<<dim3(16, 16, 4), dim3(32, 8), 0, stream>>>(Wg0, WgR, Wt0, Wt123);
    conv_mlp<<<dim3(32, 126, 3), dim3(32, 8), 0, stream>>>(Wm1, Wm2, Wm3, W1t, W2t, W3t);

    // Whole GCN (adjacency build + 4 layers + pool) in one kernel, 16 waves
    gcn_all<<<NGRAPH, 1024, GCN_LDS, stream>>>(x, esrc, edst, Wt0, Wt123, bg0, bgR, hs);

    // BN stats for h and xv (one dual-job kernel), finalize, fused att+z
    pre_stats<<<dim3(8, 16, 2), 256, 0, stream>>>(hs, x, xv, psh, pssh, psx, pssx);
    stats_fin2<<<dim3(8, 2), 256, 0, stream>>>(psh, pssh, psx, pssx, hm, hiv, xm, xi);
    attz_fused<<<NGRAPH, 256, 0, stream>>>(xv, xm, xi, gx, bx, hs, hm, hiv, gh, bh,
                                           Watt, batt, zhi, zlo);

    // MLP layer 1: [256,4032] @ [4032,1024]
    gemm_bf_sk<<<dim3(16, 4, 7), 256, 0, stream>>>(zhi, zlo, W1t, P, HID1, DCAT, 576);
    reduce_stats<<<dim3(4, 32), 256, 0, stream>>>(P, bm1, mf, ps, pss, HID1, 7);
    fin_apply<<<dim3(4, 32), 256, 0, stream>>>(ps, pss, mf, gm1, bem1, m1hi, m1lo, HID1);

    // MLP layer 2: [256,1024] @ [1024,512]
    gemm_bf_sk<<<dim3(8, 4, 8), 256, 0, stream>>>(m1hi, m1lo, W2t, P, HID2, HID1, 128);
    reduce_stats<<<dim3(2, 32), 256, 0, stream>>>(P, bm2, mf, ps, pss, HID2, 8);
    fin_apply<<<dim3(2, 32), 256, 0, stream>>>(ps, pss, mf, gm2, bem2, m2hi, m2lo, HID2);

    // MLP layer 3: [256,512] @ [512,512]
    gemm_bf_sk<<<dim3(8, 4, 8), 256, 0, stream>>>(m2hi, m2lo, W3t, P, HID2, HID2, 64);
    reduce_stats<<<dim3(2, 32), 256, 0, stream>>>(P, bm3, mf, ps, pss, HID2, 8);
    fin_apply<<<dim3(2, 32), 256, 0, stream>>>(ps, pss, mf, gm3, bem3, m3hi, m3lo, HID2);

    final_kernel<<<NGRAPH, 256, 0, stream>>>(m3hi, m3lo, Wm4, bm4, out);
}